// Round 5
// baseline (2043.138 us; speedup 1.0000x reference)
//
#include <hip/hip_runtime.h>

// ---------------------------------------------------------------------------
// B=8, N=1024, CIN=2048, HID=1024, HC=64, LV=512, NH_SSD=16, HD=128, DS=64.
// Encoder rows = 4096. Decoder collapsed to 1 row/batch. All large GEMMs:
// split-bf16 MFMA (x3 passes = f32-grade pre-quantizer; x1 post-quantizer).
// SSD intra-chunk = fused MFMA kernel (W computed in-LDS, X read chan-major).
// ---------------------------------------------------------------------------

typedef short bf16x8 __attribute__((ext_vector_type(8)));
typedef float f32x4 __attribute__((ext_vector_type(4)));

__device__ __forceinline__ unsigned short bf16_rne(float f) {
    unsigned u = __float_as_uint(f);
    unsigned r = u + 0x7FFFu + ((u >> 16) & 1u);
    return (unsigned short)(r >> 16);
}
__device__ __forceinline__ float bf16_tof(unsigned short h) {
    return __uint_as_float(((unsigned)h) << 16);
}
// Split pair: row stride 2*width ushorts; hi at [c], lo at [width+c].
__device__ __forceinline__ void store_pair(unsigned short* dst, long long row,
                                           int width, int c, float v) {
    unsigned short hi = bf16_rne(v);
    unsigned short lo = bf16_rne(v - bf16_tof(hi));
    long long base = row * (2LL * width);
    dst[base + c] = hi;
    dst[base + width + c] = lo;
}

// ---------------------------------------------------------------------------
// Reduction helpers (blockDim 256)
// ---------------------------------------------------------------------------
__device__ __forceinline__ float block_sum256(float v) {
    #pragma unroll
    for (int o = 32; o > 0; o >>= 1) v += __shfl_xor(v, o, 64);
    __shared__ float sm[4];
    int w = threadIdx.x >> 6;
    __syncthreads();
    if ((threadIdx.x & 63) == 0) sm[w] = v;
    __syncthreads();
    return sm[0] + sm[1] + sm[2] + sm[3];
}
__device__ __forceinline__ float block_max256(float v) {
    #pragma unroll
    for (int o = 32; o > 0; o >>= 1) v = fmaxf(v, __shfl_xor(v, o, 64));
    __shared__ float smx[4];
    int w = threadIdx.x >> 6;
    __syncthreads();
    if ((threadIdx.x & 63) == 0) smx[w] = v;
    __syncthreads();
    return fmaxf(fmaxf(smx[0], smx[1]), fmaxf(smx[2], smx[3]));
}

// ---------------------------------------------------------------------------
// Split-bf16 MFMA GEMM, software-pipelined K-loop (regs prefetch next tile).
// C[m,n] = alpha * sum_k A[m,k]*B[n,k] (+bias) (+res)
// NPASS=3: hh+lh+hl (f32-grade). NPASS=1: hh only.
// OUT=0: f32 C. OUT=1: split-pair C. OUT=2: transposed split-pair per 512-row
// batch (b=row>>9 -> C + b*sCb + col*ldc + (row&511), lo at +cLo).
// ---------------------------------------------------------------------------
template<int NPASS, int OUT>
__global__ __launch_bounds__(256, 2) void gemm_bf16_k(
    int M, int N, int K,
    const unsigned short* __restrict__ A2, int lda2, int aLo, long long sAb, long long sAh,
    const unsigned short* __restrict__ B2, int ldb2, int bLo, long long sBb, long long sBh,
    void* __restrict__ Cv, int ldc, int cLo, long long sCb, long long sCh,
    const float* __restrict__ bias, const float* __restrict__ res, int ldr,
    float alpha, int nh)
{
    __shared__ unsigned short Ah[128 * 40];
    __shared__ unsigned short Bh[128 * 40];
    __shared__ unsigned short Al[128 * 40];
    __shared__ unsigned short Bl[128 * 40];

    const int z  = blockIdx.z;
    const int bb = z / nh, hh = z - bb * nh;
    A2 += bb * sAb + hh * sAh;
    B2 += bb * sBb + hh * sBh;

    const int t    = threadIdx.x;
    const int m0   = blockIdx.y * 128;
    const int n0   = blockIdx.x * 128;
    const int lane = t & 63, wave = t >> 6;
    const int wm   = (wave >> 1) * 64, wn = (wave & 1) * 64;
    const int lr   = lane & 15, quad = lane >> 4;

    f32x4 acc[4][4];
    #pragma unroll
    for (int i = 0; i < 4; ++i)
        #pragma unroll
        for (int j = 0; j < 4; ++j) acc[i][j] = (f32x4){0.f, 0.f, 0.f, 0.f};

    const int srow = t >> 2;
    const int scol = (t & 3) * 8;

    uint4 rA[2], rAl[2], rB[2], rBl[2];
    // prologue: load tile k0=0 into regs
    #pragma unroll
    for (int half = 0; half < 2; ++half) {
        int r = srow + half * 64;
        const unsigned short* pA = A2 + (long long)(m0 + r) * lda2 + scol;
        rA[half] = *(const uint4*)pA;
        if (NPASS == 3) rAl[half] = *(const uint4*)(pA + aLo);
        int rb = n0 + r;
        uint4 z4 = {0u, 0u, 0u, 0u};
        rB[half] = z4; rBl[half] = z4;
        if (rb < N) {
            const unsigned short* pB = B2 + (long long)rb * ldb2 + scol;
            rB[half] = *(const uint4*)pB;
            if (NPASS == 3) rBl[half] = *(const uint4*)(pB + bLo);
        }
    }

    for (int k0 = 0; k0 < K; k0 += 32) {
        __syncthreads();
        #pragma unroll
        for (int half = 0; half < 2; ++half) {
            int r = srow + half * 64;
            *(uint4*)&Ah[r * 40 + scol] = rA[half];
            *(uint4*)&Bh[r * 40 + scol] = rB[half];
            if (NPASS == 3) {
                *(uint4*)&Al[r * 40 + scol] = rAl[half];
                *(uint4*)&Bl[r * 40 + scol] = rBl[half];
            }
        }
        __syncthreads();
        int k1 = k0 + 32;
        if (k1 < K) {
            #pragma unroll
            for (int half = 0; half < 2; ++half) {
                int r = srow + half * 64;
                const unsigned short* pA = A2 + (long long)(m0 + r) * lda2 + k1 + scol;
                rA[half] = *(const uint4*)pA;
                if (NPASS == 3) rAl[half] = *(const uint4*)(pA + aLo);
                int rb = n0 + r;
                uint4 z4 = {0u, 0u, 0u, 0u};
                rB[half] = z4; rBl[half] = z4;
                if (rb < N) {
                    const unsigned short* pB = B2 + (long long)rb * ldb2 + k1 + scol;
                    rB[half] = *(const uint4*)pB;
                    if (NPASS == 3) rBl[half] = *(const uint4*)(pB + bLo);
                }
            }
        }

        bf16x8 ah[4], bh[4], al[4], bl[4];
        #pragma unroll
        for (int i = 0; i < 4; ++i) {
            int ra = (wm + i * 16 + lr) * 40 + quad * 8;
            int rb = (wn + i * 16 + lr) * 40 + quad * 8;
            ah[i] = *(const bf16x8*)&Ah[ra];
            bh[i] = *(const bf16x8*)&Bh[rb];
            if (NPASS == 3) {
                al[i] = *(const bf16x8*)&Al[ra];
                bl[i] = *(const bf16x8*)&Bl[rb];
            }
        }
        #pragma unroll
        for (int mi = 0; mi < 4; ++mi)
            #pragma unroll
            for (int ni = 0; ni < 4; ++ni) {
                acc[mi][ni] = __builtin_amdgcn_mfma_f32_16x16x32_bf16(
                    ah[mi], bh[ni], acc[mi][ni], 0, 0, 0);
                if (NPASS == 3) {
                    acc[mi][ni] = __builtin_amdgcn_mfma_f32_16x16x32_bf16(
                        al[mi], bh[ni], acc[mi][ni], 0, 0, 0);
                    acc[mi][ni] = __builtin_amdgcn_mfma_f32_16x16x32_bf16(
                        ah[mi], bl[ni], acc[mi][ni], 0, 0, 0);
                }
            }
    }

    // D layout: col = lane&15, row = quad*4 + r
    if (OUT == 0) {
        float* C = (float*)Cv + bb * sCb + hh * sCh;
        #pragma unroll
        for (int mi = 0; mi < 4; ++mi)
            #pragma unroll
            for (int ni = 0; ni < 4; ++ni) {
                int col = n0 + wn + ni * 16 + lr;
                if (col >= N) continue;
                float bv = bias ? bias[col] : 0.f;
                #pragma unroll
                for (int r = 0; r < 4; ++r) {
                    int row = m0 + wm + mi * 16 + quad * 4 + r;
                    float v = alpha * acc[mi][ni][r] + bv;
                    if (res) v += res[(long long)row * ldr + col];
                    C[(long long)row * ldc + col] = v;
                }
            }
    } else if (OUT == 1) {
        unsigned short* C = (unsigned short*)Cv + bb * sCb + hh * sCh;
        #pragma unroll
        for (int mi = 0; mi < 4; ++mi)
            #pragma unroll
            for (int ni = 0; ni < 4; ++ni) {
                int col = n0 + wn + ni * 16 + lr;
                if (col >= N) continue;
                float bv = bias ? bias[col] : 0.f;
                #pragma unroll
                for (int r = 0; r < 4; ++r) {
                    int row = m0 + wm + mi * 16 + quad * 4 + r;
                    float v = alpha * acc[mi][ni][r] + bv;
                    if (res) v += res[(long long)row * ldr + col];
                    unsigned short hi = bf16_rne(v);
                    unsigned short lo = bf16_rne(v - bf16_tof(hi));
                    long long p = (long long)row * ldc + col;
                    C[p] = hi;
                    C[p + cLo] = lo;
                }
            }
    } else {  // OUT == 2: transposed pairs per 512-row batch
        unsigned short* C = (unsigned short*)Cv;
        #pragma unroll
        for (int mi = 0; mi < 4; ++mi)
            #pragma unroll
            for (int ni = 0; ni < 4; ++ni) {
                int col = n0 + wn + ni * 16 + lr;
                if (col >= N) continue;
                int row0 = m0 + wm + mi * 16 + quad * 4;
                int b = row0 >> 9, seq0 = row0 & 511;
                ushort4 h4, l4;
                unsigned short* hp = (unsigned short*)&h4;
                unsigned short* lp = (unsigned short*)&l4;
                #pragma unroll
                for (int r = 0; r < 4; ++r) {
                    float v = acc[mi][ni][r];
                    unsigned short hi = bf16_rne(v);
                    hp[r] = hi;
                    lp[r] = bf16_rne(v - bf16_tof(hi));
                }
                long long p = b * sCb + (long long)col * ldc + seq0;
                *(ushort4*)&C[p] = h4;
                *(ushort4*)&C[p + cLo] = l4;
            }
    }
}

// ---------------------------------------------------------------------------
// Fused SSD intra-chunk MFMA kernel.
// Per (b,h): Y[l,p] = sum_{s<=l} W[l,s]*XC[s,p], W = G*exp(cAl-cAs)*dt[s].
// W computed into LDS as split-bf16 pairs; X read directly from chan-major
// global pairs XCT2[b][chan][seq] as MFMA B-fragments. 3-pass split precision.
// Epilogue: (Y + XC*D) * silu(Z) -> seq-major pairs YS2.
// grid (4 l-tiles, 16 h, 8 b), block 256.
// ---------------------------------------------------------------------------
__global__ __launch_bounds__(256, 2) void ssd_mfma_k(
    const float* __restrict__ G, const float* __restrict__ CUMA,
    const float* __restrict__ DT, const unsigned short* __restrict__ XCT2,
    const unsigned short* __restrict__ ZT2, const float* __restrict__ Dv,
    unsigned short* __restrict__ YS2)
{
    __shared__ unsigned short Ah[128 * 40];
    __shared__ unsigned short Al[128 * 40];
    const int mt = blockIdx.x, h = blockIdx.y, b = blockIdx.z;
    const int t = threadIdx.x;
    const int lane = t & 63, wave = t >> 6;
    const int wm = (wave >> 1) * 64, wn = (wave & 1) * 64;
    const int lr = lane & 15, quad = lane >> 4;
    const int m0 = mt * 128;

    // W staging: thread handles l = t>>1, s in [ws0, ws0+16)
    const int wl = t >> 1;
    const int ws0 = (t & 1) * 16;
    const int lglob = m0 + wl;
    const float* cbase = CUMA + (b * 16 + h) * 512;
    const float cAl = cbase[lglob];
    const float* gbase = G + ((long long)(b * 512 + lglob)) * 512;
    const float* dtb = DT + (long long)b * 512 * 16 + h;

    f32x4 acc[4][4];
    #pragma unroll
    for (int i = 0; i < 4; ++i)
        #pragma unroll
        for (int j = 0; j < 4; ++j) acc[i][j] = (f32x4){0.f, 0.f, 0.f, 0.f};

    const unsigned short* XB = XCT2 + (long long)b * 2097152 + (long long)(h * 128) * 1024;

    const int kend = (mt + 1) * 128;
    for (int k0 = 0; k0 < kend; k0 += 32) {
        __syncthreads();
        #pragma unroll
        for (int jj = 0; jj < 4; ++jj) {
            int s0 = k0 + ws0 + jj * 4;
            float4 g = *(const float4*)(gbase + s0);
            float gv[4] = {g.x, g.y, g.z, g.w};
            #pragma unroll
            for (int e = 0; e < 4; ++e) {
                int sg = s0 + e;
                float w = 0.f;
                if (sg <= lglob)
                    w = gv[e] * expf(cAl - cbase[sg]) * dtb[(long long)sg * 16];
                unsigned short hi = bf16_rne(w);
                unsigned short lo = bf16_rne(w - bf16_tof(hi));
                Ah[wl * 40 + ws0 + jj * 4 + e] = hi;
                Al[wl * 40 + ws0 + jj * 4 + e] = lo;
            }
        }
        __syncthreads();
        bf16x8 ah[4], al[4];
        #pragma unroll
        for (int i = 0; i < 4; ++i) {
            int ra = (wm + i * 16 + lr) * 40 + quad * 8;
            ah[i] = *(const bf16x8*)&Ah[ra];
            al[i] = *(const bf16x8*)&Al[ra];
        }
        #pragma unroll
        for (int ni = 0; ni < 4; ++ni) {
            const unsigned short* pB = XB + (long long)(wn + ni * 16 + lr) * 1024 + k0 + quad * 8;
            bf16x8 bh = *(const bf16x8*)pB;
            bf16x8 bl = *(const bf16x8*)(pB + 512);
            #pragma unroll
            for (int mi = 0; mi < 4; ++mi) {
                acc[mi][ni] = __builtin_amdgcn_mfma_f32_16x16x32_bf16(
                    ah[mi], bh, acc[mi][ni], 0, 0, 0);
                acc[mi][ni] = __builtin_amdgcn_mfma_f32_16x16x32_bf16(
                    al[mi], bh, acc[mi][ni], 0, 0, 0);
                acc[mi][ni] = __builtin_amdgcn_mfma_f32_16x16x32_bf16(
                    ah[mi], bl, acc[mi][ni], 0, 0, 0);
            }
        }
    }

    const float Dh = Dv[h];
    #pragma unroll
    for (int mi = 0; mi < 4; ++mi)
        #pragma unroll
        for (int ni = 0; ni < 4; ++ni) {
            int p = wn + ni * 16 + lr;
            int chan = h * 128 + p;
            int row0 = m0 + wm + mi * 16 + quad * 4;
            long long cb = (long long)b * 2097152 + (long long)chan * 1024 + row0;
            ushort4 xh = *(const ushort4*)(XCT2 + cb);
            ushort4 xl = *(const ushort4*)(XCT2 + cb + 512);
            ushort4 zh = *(const ushort4*)(ZT2 + cb);
            ushort4 zl = *(const ushort4*)(ZT2 + cb + 512);
            const unsigned short* xhp = (const unsigned short*)&xh;
            const unsigned short* xlp = (const unsigned short*)&xl;
            const unsigned short* zhp = (const unsigned short*)&zh;
            const unsigned short* zlp = (const unsigned short*)&zl;
            #pragma unroll
            for (int r = 0; r < 4; ++r) {
                float xc = bf16_tof(xhp[r]) + bf16_tof(xlp[r]);
                float zz = bf16_tof(zhp[r]) + bf16_tof(zlp[r]);
                float y = (acc[mi][ni][r] + xc * Dh) * (zz / (1.f + expf(-zz)));
                store_pair(YS2, (long long)(b * 512 + row0 + r), 2048, chan, y);
            }
        }
}

// ---------------------------------------------------------------------------
// Tiled f32 GEMM (only for the small batched G = Cm @ Bm^T)
// ---------------------------------------------------------------------------
__global__ __launch_bounds__(256) void gemm_f32_k(
    int M, int N, int K,
    const float* __restrict__ A, int lda, long long sAb,
    const float* __restrict__ B, int ldb, long long sBb,
    float* __restrict__ C, int ldc, long long sCb)
{
    __shared__ float As[32][132];
    __shared__ float Bs[32][132];
    const int z = blockIdx.z;
    A += z * sAb; B += z * sBb; C += z * sCb;
    const int n0 = blockIdx.x * 128;
    const int m0 = blockIdx.y * 128;
    const int t  = threadIdx.x;
    const int tx = t & 15, ty = t >> 4;

    float acc[4][16];
    #pragma unroll
    for (int a = 0; a < 4; ++a)
        #pragma unroll
        for (int q = 0; q < 16; ++q) acc[a][q] = 0.f;

    const int ka = (t & 7) << 2;
    const int ra = t >> 3;

    for (int k0 = 0; k0 < K; k0 += 32) {
        __syncthreads();
        #pragma unroll
        for (int i = 0; i < 4; ++i) {
            int row = m0 + ra + i * 32;
            float4 v = *(const float4*)(A + (long long)row * lda + (k0 + ka));
            As[ka + 0][ra + i * 32] = v.x;
            As[ka + 1][ra + i * 32] = v.y;
            As[ka + 2][ra + i * 32] = v.z;
            As[ka + 3][ra + i * 32] = v.w;
            int rowb = n0 + ra + i * 32;
            float4 w = *(const float4*)(B + (long long)rowb * ldb + (k0 + ka));
            Bs[ka + 0][ra + i * 32] = w.x;
            Bs[ka + 1][ra + i * 32] = w.y;
            Bs[ka + 2][ra + i * 32] = w.z;
            Bs[ka + 3][ra + i * 32] = w.w;
        }
        __syncthreads();
        #pragma unroll
        for (int kk = 0; kk < 32; ++kk) {
            float a[8], bm[8];
            *(float4*)&a[0]  = *(const float4*)&As[kk][ty * 4];
            *(float4*)&a[4]  = *(const float4*)&As[kk][64 + ty * 4];
            *(float4*)&bm[0] = *(const float4*)&Bs[kk][tx * 4];
            *(float4*)&bm[4] = *(const float4*)&Bs[kk][64 + tx * 4];
            #pragma unroll
            for (int ri = 0; ri < 2; ++ri)
                #pragma unroll
                for (int ci = 0; ci < 2; ++ci)
                    #pragma unroll
                    for (int i = 0; i < 4; ++i)
                        #pragma unroll
                        for (int j = 0; j < 4; ++j)
                            acc[ri * 2 + ci][i * 4 + j] =
                                fmaf(a[ri * 4 + i], bm[ci * 4 + j], acc[ri * 2 + ci][i * 4 + j]);
        }
    }
    #pragma unroll
    for (int ri = 0; ri < 2; ++ri)
        #pragma unroll
        for (int ci = 0; ci < 2; ++ci) {
            int colb = n0 + ci * 64 + tx * 4;
            #pragma unroll
            for (int i = 0; i < 4; ++i) {
                int row = m0 + ri * 64 + ty * 4 + i;
                *(float4*)(C + (long long)row * ldc + colb) =
                    *(float4*)&acc[ri * 2 + ci][i * 4];
            }
        }
}

// ---------------------------------------------------------------------------
// Elementwise / norm kernels
// ---------------------------------------------------------------------------
__global__ __launch_bounds__(256) void pairify_k(
    const float* __restrict__ src, unsigned short* __restrict__ dst,
    int k_log2, long long n)
{
    long long idx = (long long)blockIdx.x * 256 + threadIdx.x;
    if (idx >= n) return;
    long long r = idx >> k_log2;
    int c = (int)(idx & ((1 << k_log2) - 1));
    store_pair(dst, r, 1 << k_log2, c, src[idx]);
}

__global__ __launch_bounds__(256) void layernorm_k(
    const float* __restrict__ in, float* __restrict__ out,
    const float* __restrict__ w, const float* __restrict__ b,
    int width, int rows_per_b, long long in_bstride)
{
    long long r = blockIdx.x;
    const float* x = in + (r / rows_per_b) * in_bstride + (r % rows_per_b) * (long long)width;
    int t = threadIdx.x;
    float s = 0.f;
    for (int c = t; c < width; c += 256) s += x[c];
    s = block_sum256(s);
    float m = s / (float)width;
    float vs = 0.f;
    for (int c = t; c < width; c += 256) { float d = x[c] - m; vs += d * d; }
    vs = block_sum256(vs);
    float rs = 1.f / sqrtf(vs / (float)width + 1e-5f);
    float* o = out + r * (long long)width;
    for (int c = t; c < width; c += 256) o[c] = (x[c] - m) * rs * w[c] + b[c];
}

__global__ __launch_bounds__(256) void layernorm_pair_k(
    const float* __restrict__ in, unsigned short* __restrict__ out2,
    const float* __restrict__ w, const float* __restrict__ b,
    int width, int rows_per_b, long long in_bstride)
{
    long long r = blockIdx.x;
    const float* x = in + (r / rows_per_b) * in_bstride + (r % rows_per_b) * (long long)width;
    int t = threadIdx.x;
    float s = 0.f;
    for (int c = t; c < width; c += 256) s += x[c];
    s = block_sum256(s);
    float m = s / (float)width;
    float vs = 0.f;
    for (int c = t; c < width; c += 256) { float d = x[c] - m; vs += d * d; }
    vs = block_sum256(vs);
    float rs = 1.f / sqrtf(vs / (float)width + 1e-5f);
    for (int c = t; c < width; c += 256)
        store_pair(out2, r, width, c, (x[c] - m) * rs * w[c] + b[c]);
}

__global__ __launch_bounds__(256) void rmsnorm_pair_k(
    const float* __restrict__ in, unsigned short* __restrict__ out2,
    const float* __restrict__ w, int width)
{
    long long r = blockIdx.x;
    const float* x = in + r * (long long)width;
    int t = threadIdx.x;
    float s = 0.f;
    for (int c = t; c < width; c += 256) { float v = x[c]; s += v * v; }
    s = block_sum256(s);
    float rs = 1.f / sqrtf(s / (float)width + 1e-5f);
    for (int c = t; c < width; c += 256)
        store_pair(out2, r, width, c, x[c] * rs * w[c]);
}

// Softmax over 512-wide rows, f32 in -> split-pair out IN-PLACE (same bytes).
__global__ __launch_bounds__(256) void softmax_pair_k(float* __restrict__ S,
                                                      unsigned short* __restrict__ P2)
{
    long long r = blockIdx.x;
    float* x = S + r * 512;
    unsigned short* p = P2 + r * 1024;
    int t = threadIdx.x;
    float v0 = x[t], v1 = x[t + 256];
    float mx = block_max256(fmaxf(v0, v1));
    v0 = expf(v0 - mx); v1 = expf(v1 - mx);
    float sum = block_sum256(v0 + v1);
    float inv = 1.f / sum;
    v0 *= inv; v1 *= inv;
    __syncthreads();
    unsigned short h0 = bf16_rne(v0);
    p[t] = h0;       p[512 + t] = bf16_rne(v0 - bf16_tof(h0));
    unsigned short h1 = bf16_rne(v1);
    p[t + 256] = h1; p[512 + t + 256] = bf16_rne(v1 - bf16_tof(h1));
}

// Causal grouped conv -> seq-major pairs XC2 AND chan-major pairs XCT2.
__global__ __launch_bounds__(256) void conv_k(
    const float* __restrict__ XS, const float* __restrict__ W,
    unsigned short* __restrict__ XC2, unsigned short* __restrict__ XCT2)
{
    int idx = blockIdx.x * 256 + threadIdx.x;
    int o = idx & 2047;
    int tt = (idx >> 11) & 511;
    int b = idx >> 20;
    int g2 = (o >> 1) << 1;
    const float* Wo = W + o * 8;
    float acc = 0.f;
    #pragma unroll
    for (int k = 0; k < 4; ++k) {
        int ts = tt + k - 3;
        if (ts >= 0) {
            const float* xr = XS + ((long long)(b * 512 + ts)) * 2048;
            acc = fmaf(Wo[k], xr[g2], acc);
            acc = fmaf(Wo[4 + k], xr[g2 + 1], acc);
        }
    }
    unsigned short hi = bf16_rne(acc);
    unsigned short lo = bf16_rne(acc - bf16_tof(hi));
    long long row = (long long)(b * 512 + tt);
    XC2[row * 4096 + o] = hi;
    XC2[row * 4096 + 2048 + o] = lo;
    long long tb = (long long)b * 2097152 + (long long)o * 1024 + tt;
    XCT2[tb] = hi;
    XCT2[tb + 512] = lo;
}

__global__ __launch_bounds__(256) void dt_k(
    const float* __restrict__ dtBC, const float* __restrict__ dt_bias, float* __restrict__ DT)
{
    int idx = blockIdx.x * 256 + threadIdx.x;
    int r = idx >> 4, h = idx & 15;
    float xv = dtBC[r * 144 + h] + dt_bias[h];
    DT[idx] = (xv > 20.f) ? xv : log1pf(expf(xv));
}

__global__ __launch_bounds__(64) void cuma_k(
    const float* __restrict__ DT, const float* __restrict__ A_log, float* __restrict__ CUMA)
{
    int h = blockIdx.x, b = blockIdx.y;
    int ln = threadIdx.x;
    float Ah = -expf(A_log[h]);
    float v[8];
    float run = 0.f;
    #pragma unroll
    for (int i = 0; i < 8; ++i) {
        run += Ah * DT[((b * 512) + (ln * 8 + i)) * 16 + h];
        v[i] = run;
    }
    float tot = run;
    float sc = tot;
    #pragma unroll
    for (int o = 1; o <= 32; o <<= 1) {
        float u = __shfl_up(sc, o, 64);
        if (ln >= o) sc += u;
    }
    float excl = sc - tot;
    #pragma unroll
    for (int i = 0; i < 8; ++i)
        CUMA[(b * 16 + h) * 512 + ln * 8 + i] = excl + v[i];
}

// hc = LayerNorm64(G1) -> {-1,+1} as split pairs (lo = 0)
__global__ __launch_bounds__(64) void hc_quant_k(
    const float* __restrict__ G1, const float* __restrict__ w,
    const float* __restrict__ b, unsigned short* __restrict__ HCQ2)
{
    int r = blockIdx.x, ln = threadIdx.x;
    float v = G1[r * 64 + ln];
    float s = v;
    #pragma unroll
    for (int o = 32; o > 0; o >>= 1) s += __shfl_xor(s, o, 64);
    float m = s * (1.f / 64.f);
    float d = v - m;
    float vs = d * d;
    #pragma unroll
    for (int o = 32; o > 0; o >>= 1) vs += __shfl_xor(vs, o, 64);
    vs *= (1.f / 64.f);
    float hc = d * (1.f / sqrtf(vs + 1e-5f)) * w[ln] + b[ln];
    HCQ2[r * 128 + ln] = (hc > 0.f) ? 0x3F80 : 0xBF80;
    HCQ2[r * 128 + 64 + ln] = 0;
}

__global__ __launch_bounds__(256) void dxm_k(
    const float* __restrict__ mtok, const float* __restrict__ e2d, float* __restrict__ dxm)
{
    int c = blockIdx.x * 256 + threadIdx.x;
    float acc = 0.f;
    #pragma unroll
    for (int j = 0; j < 64; ++j) acc = fmaf(mtok[j], e2d[c * 64 + j], acc);
    dxm[c] = acc;
}

__global__ __launch_bounds__(256) void projm_k(
    const float* __restrict__ lnm,
    const float* __restrict__ bWq, const float* __restrict__ bWk, const float* __restrict__ bWv,
    float* __restrict__ qm, float* __restrict__ km, float* __restrict__ vm)
{
    int idx = blockIdx.x * 256 + threadIdx.x;
    int sel = idx >> 10, c = idx & 1023;
    const float* W = (sel == 0) ? bWq : (sel == 1) ? bWk : bWv;
    float* O = (sel == 0) ? qm : (sel == 1) ? km : vm;
    const float* wr = W + (long long)c * 1024;
    float acc = 0.f;
    for (int j = 0; j < 1024; j += 4) {
        float4 a = *(const float4*)(lnm + j);
        float4 w4 = *(const float4*)(wr + j);
        acc = fmaf(a.x, w4.x, fmaf(a.y, w4.y, fmaf(a.z, w4.z, fmaf(a.w, w4.w, acc))));
    }
    O[c] = acc;
}

// Collapsed decoder attention: 1 query/(b,h); keys = 512 visible + mask key x512.
__global__ __launch_bounds__(256) void dec_attn_k(
    const float* __restrict__ Kv, const float* __restrict__ Vv,
    const float* __restrict__ qm, const float* __restrict__ km,
    const float* __restrict__ vm, float* __restrict__ OBm)
{
    int h = blockIdx.x, b = blockIdx.y;
    int t = threadIdx.x;
    __shared__ __align__(16) float qs[256];
    __shared__ __align__(16) float ps[512];
    qs[t] = qm[h * 256 + t];
    __syncthreads();
    float s[2];
    #pragma unroll
    for (int i = 0; i < 2; ++i) {
        int r = t + i * 256;
        const float* kr = Kv + ((long long)(b * 512 + r)) * 1024 + h * 256;
        float acc = 0.f;
        for (int c = 0; c < 256; c += 4) {
            float4 k4 = *(const float4*)(kr + c);
            float4 q4 = *(const float4*)(qs + c);
            acc = fmaf(k4.x, q4.x, fmaf(k4.y, q4.y, fmaf(k4.z, q4.z, fmaf(k4.w, q4.w, acc))));
        }
        s[i] = acc * (1.f / 16.f);
    }
    float accm = 0.f;
    for (int c = 0; c < 256; c += 4) {
        float4 k4 = *(const float4*)(km + h * 256 + c);
        float4 q4 = *(const float4*)(qs + c);
        accm = fmaf(k4.x, q4.x, fmaf(k4.y, q4.y, fmaf(k4.z, q4.z, fmaf(k4.w, q4.w, accm))));
    }
    float smv = accm * (1.f / 16.f);
    float mx = block_max256(fmaxf(fmaxf(s[0], s[1]), smv));
    float p0 = expf(s[0] - mx), p1 = expf(s[1] - mx);
    ps[t] = p0; ps[t + 256] = p1;
    float pm = expf(smv - mx) * 512.f;
    float sum = block_sum256(p0 + p1) + pm;
    float inv = 1.f / sum;
    __syncthreads();
    float o = pm * vm[h * 256 + t];
    const float* vcol = Vv + (long long)b * 512 * 1024 + h * 256 + t;
    for (int j = 0; j < 512; ++j)
        o = fmaf(ps[j], vcol[(long long)j * 1024], o);
    OBm[b * 1024 + h * 256 + t] = o * inv;
}

__global__ __launch_bounds__(256) void ydm_k(
    const float* __restrict__ OBm, const float* __restrict__ bWo,
    const float* __restrict__ bWo_b, const float* __restrict__ dxm,
    float* __restrict__ ydm)
{
    int idx = blockIdx.x * 256 + threadIdx.x;
    int b = idx >> 10, c = idx & 1023;
    const float* ar = OBm + b * 1024;
    const float* wr = bWo + (long long)c * 1024;
    float acc = 0.f;
    for (int j = 0; j < 1024; j += 4) {
        float4 a = *(const float4*)(ar + j);
        float4 w4 = *(const float4*)(wr + j);
        acc = fmaf(a.x, w4.x, fmaf(a.y, w4.y, fmaf(a.z, w4.z, fmaf(a.w, w4.w, acc))));
    }
    ydm[idx] = acc + bWo_b[c] + dxm[c];
}

__global__ __launch_bounds__(256) void outm_k(
    const float* __restrict__ ydm, const float* __restrict__ dout_W,
    const float* __restrict__ dout_b, float* __restrict__ outm)
{
    int idx = blockIdx.x * 256 + threadIdx.x;
    int b = idx >> 11, c = idx & 2047;
    const float* ar = ydm + b * 1024;
    const float* wr = dout_W + (long long)c * 1024;
    float acc = 0.f;
    for (int j = 0; j < 1024; j += 4) {
        float4 a = *(const float4*)(ar + j);
        float4 w4 = *(const float4*)(wr + j);
        acc = fmaf(a.x, w4.x, fmaf(a.y, w4.y, fmaf(a.z, w4.z, fmaf(a.w, w4.w, acc))));
    }
    outm[idx] = acc + dout_b[c];
}

__global__ __launch_bounds__(256) void bcast_k(
    const float* __restrict__ outm, float* __restrict__ out)
{
    int idx = blockIdx.x * 256 + threadIdx.x;
    int c4 = idx & 511;
    int b = idx >> 18;
    ((float4*)out)[idx] = ((const float4*)outm)[b * 512 + c4];
}

// ---------------------------------------------------------------------------
// Host-side launcher
// ---------------------------------------------------------------------------
static inline void pairify(hipStream_t s, const float* src, unsigned short* dst,
                           int k_log2, long long n)
{
    pairify_k<<<(int)((n + 255) / 256), 256, 0, s>>>(src, dst, k_log2, n);
}

extern "C" void kernel_launch(void* const* d_in, const int* in_sizes, int n_in,
                              void* d_out, int out_size, void* d_ws, size_t ws_size,
                              hipStream_t stream)
{
    const float* x       = (const float*)d_in[0];
    const float* ln0_w   = (const float*)d_in[1];
    const float* ln0_b   = (const float*)d_in[2];
    const float* in_W    = (const float*)d_in[3];
    const float* rms_w   = (const float*)d_in[4];
    const float* exp_W   = (const float*)d_in[5];
    const float* conv_W  = (const float*)d_in[6];
    const float* xproj_W = (const float*)d_in[7];
    const float* dt_bias = (const float*)d_in[8];
    const float* A_log   = (const float*)d_in[9];
    const float* Dv      = (const float*)d_in[10];
    const float* outp_W  = (const float*)d_in[11];
    const float* outp_b  = (const float*)d_in[12];
    const float* n1_w    = (const float*)d_in[13];
    const float* n1_b    = (const float*)d_in[14];
    const float* aWq     = (const float*)d_in[15];
    const float* aWk     = (const float*)d_in[16];
    const float* aWv     = (const float*)d_in[17];
    const float* aWo     = (const float*)d_in[18];
    const float* aWo_b   = (const float*)d_in[19];
    const float* h_W     = (const float*)d_in[20];
    const float* h_b     = (const float*)d_in[21];
    const float* h_lnw   = (const float*)d_in[22];
    const float* h_lnb   = (const float*)d_in[23];
    const float* mtok    = (const float*)d_in[24];
    const float* e2d_W   = (const float*)d_in[25];
    const float* dn_w    = (const float*)d_in[26];
    const float* dn_b    = (const float*)d_in[27];
    const float* bWq     = (const float*)d_in[28];
    const float* bWk     = (const float*)d_in[29];
    const float* bWv     = (const float*)d_in[30];
    const float* bWo     = (const float*)d_in[31];
    const float* bWo_b   = (const float*)d_in[32];
    const float* dout_W  = (const float*)d_in[33];
    const float* dout_b  = (const float*)d_in[34];

    float* ws  = (float*)d_ws;
    float* out = (float*)d_out;

    // ---- slots (float offsets) ----
    // S1 8.39M: XV2 | exp_W2 | XCT2 | SA/P2 | Kv+Vv
    // S2 8.39M: in_W2 | XS | YS2
    // S3 8.39M: XC2 | outp_W2 | DXV + LNDXV2
    // S4 8.39M: ZT2 | aW{q,k,v,o}2 + bW{k,v}2
    // S5 4.19M: T | QA2 | Y22      S6: HR2 | Y1      S7: LNY2 | OA2
    // S8 4.19M: KA2                S9: VT2           SP: small pool
    float* S1 = ws;
    float* S2 = ws + 8388608;
    float* S3 = ws + 16777216;
    float* S4 = ws + 25165824;
    float* S5 = ws + 33554432;
    float* S6 = ws + 37748736;
    float* S7 = ws + 41943040;
    float* S8 = ws + 46137344;
    float* S9 = ws + 50331648;
    float* SP = ws + 54525952;

    unsigned short* XV2     = (unsigned short*)S1;
    unsigned short* exp_W2  = (unsigned short*)S1;
    unsigned short* XCT2    = (unsigned short*)S1;
    float*          SA      = S1;
    unsigned short* P2      = (unsigned short*)S1;
    float*          Kv      = S1;
    float*          Vv      = S1 + 4194304;
    unsigned short* in_W2   = (unsigned short*)S2;
    float*          XS      = S2;
    unsigned short* YS2     = (unsigned short*)S2;
    unsigned short* XC2     = (unsigned short*)S3;
    unsigned short* outp_W2 = (unsigned short*)S3;
    float*          DXV     = S3;
    unsigned short* LNDXV2  = (unsigned short*)(S3 + 4194304);
    unsigned short* ZT2     = (unsigned short*)S4;
    unsigned short* aWq2    = (unsigned short*)S4;
    unsigned short* aWk2    = (unsigned short*)S4 + 2097152;
    unsigned short* aWv2    = (unsigned short*)S4 + 4194304;
    unsigned short* aWo2    = (unsigned short*)S4 + 6291456;
    unsigned short* bWk2    = (unsigned short*)S4 + 8388608;
    unsigned short* bWv2    = (unsigned short*)S4 + 10485760;
    float*          T       = S5;
    unsigned short* QA2     = (unsigned short*)S5;
    unsigned short* Y22     = (unsigned short*)S5;
    unsigned short* HR2     = (unsigned short*)S6;
    float*          Y1      = S6;
    unsigned short* LNY2    = (unsigned short*)S7;
    unsigned short* OA2     = (unsigned short*)S7;
    unsigned short* KA2     = (unsigned short*)S8;
    unsigned short* VT2     = (unsigned short*)S9;

    float* dtBC = SP;                     // 589,824
    float* DT   = SP + 589824;            // 65,536
    float* CUMA = SP + 655360;            // 65,536
    float* G    = SP + 720896;            // 2,097,152  [live: G GEMM -> ssd]
    unsigned short* xprojW2 = (unsigned short*)(SP + 2818048);  // 294,912 fl
    unsigned short* hW2     = (unsigned short*)(SP + 3112960);  // 65,536 fl
    unsigned short* e2dW2   = (unsigned short*)(SP + 3178496);  // 65,536 fl
    float* G1   = SP + 720896;            // alias over dead G
    unsigned short* HCQ2 = (unsigned short*)(SP + 983040);      // 262,144 fl
    float* dxm  = SP + 1245184;
    float* lnm  = SP + 1246208;
    float* qm   = SP + 1247232;
    float* km   = SP + 1248256;
    float* vm   = SP + 1249280;
    float* OBm  = SP + 1250304;
    float* ydm  = SP + 1258496;
    float* outm = SP + 1266688;

    const long long LL0 = 0;
    #define G3(OUTM, GX, GY, GZ, ...) \
        gemm_bf16_k<3, OUTM><<<dim3(GX, GY, GZ), 256, 0, stream>>>(__VA_ARGS__)
    #define G1P(OUTM, GX, GY, GZ, ...) \
        gemm_bf16_k<1, OUTM><<<dim3(GX, GY, GZ), 256, 0, stream>>>(__VA_ARGS__)

    // ---- weight prep (phase A) ----
    pairify(stream, in_W,    in_W2,   11, 1024LL * 2048);
    pairify(stream, xproj_W, xprojW2, 11, 144LL * 2048);
    pairify(stream, h_W,     hW2,     10, 64LL * 1024);
    pairify(stream, e2d_W,   e2dW2,    6, 1024LL * 64);

    // ---- encoder trunk ----
    layernorm_pair_k<<<4096, 256, 0, stream>>>(x, XV2, ln0_w, ln0_b, 2048, 512,
                                               (long long)1024 * 2048);
    G3(0, 8, 32, 1, 4096, 1024, 2048, XV2, 4096, 2048, LL0, LL0,
       in_W2, 4096, 2048, LL0, LL0, T, 1024, 0, LL0, LL0,
       nullptr, nullptr, 0, 1.f, 1);
    pairify(stream, exp_W, exp_W2, 10, 4096LL * 1024);   // S1 (XV2 dead)
    rmsnorm_pair_k<<<4096, 256, 0, stream>>>(T, HR2, rms_w, 1024);
    G3(0, 16, 32, 1, 4096, 2048, 1024, HR2, 2048, 1024, LL0, LL0,
       exp_W2, 2048, 1024, LL0, LL0, XS, 2048, 0, LL0, LL0,
       nullptr, nullptr, 0, 1.f, 1);
    // Z -> transposed pairs ZT2 (chan-major per batch)
    G3(2, 16, 32, 1, 4096, 2048, 1024, HR2, 2048, 1024, LL0, LL0,
       exp_W2 + 2048LL * 2048, 2048, 1024, LL0, LL0,
       ZT2, 1024, 512, (long long)2048 * 1024, LL0,
       nullptr, nullptr, 0, 1.f, 1);
    // conv: writes XC2 (seq-major) + XCT2 (chan-major, over dead exp_W2/S1)
    conv_k<<<32768, 256, 0, stream>>>(XS, conv_W, XC2, XCT2);
    G3(0, 2, 32, 1, 4096, 144, 2048, XC2, 4096, 2048, LL0, LL0,
       xprojW2, 4096, 2048, LL0, LL0, dtBC, 144, 0, LL0, LL0,
       nullptr, nullptr, 0, 1.f, 1);
    dt_k<<<256, 256, 0, stream>>>(dtBC, dt_bias, DT);
    cuma_k<<<dim3(16, 8), 64, 0, stream>>>(DT, A_log, CUMA);
    gemm_f32_k<<<dim3(4, 4, 8), 256, 0, stream>>>(
        512, 512, 64, dtBC + 80, 144, (long long)512 * 144,
        dtBC + 16, 144, (long long)512 * 144, G, 512, (long long)512 * 512);
    ssd_mfma_k<<<dim3(4, 16, 8), 256, 0, stream>>>(G, CUMA, DT, XCT2, ZT2, Dv, YS2);

    // ---- weight prep (phase B: S3/S4 now dead) ----
    pairify(stream, outp_W, outp_W2, 11, 1024LL * 2048);
    pairify(stream, aWq, aWq2, 10, 1024LL * 1024);
    pairify(stream, aWk, aWk2, 10, 1024LL * 1024);
    pairify(stream, aWv, aWv2, 10, 1024LL * 1024);
    pairify(stream, aWo, aWo2, 10, 1024LL * 1024);
    pairify(stream, bWk, bWk2, 10, 1024LL * 1024);
    pairify(stream, bWv, bWv2, 10, 1024LL * 1024);

    G3(0, 8, 32, 1, 4096, 1024, 2048, YS2, 4096, 2048, LL0, LL0,
       outp_W2, 4096, 2048, LL0, LL0, Y1, 1024, 0, LL0, LL0,
       outp_b, T, 1024, 1.f, 1);

    // ---- encoder attention (all MFMA) ----
    layernorm_pair_k<<<4096, 256, 0, stream>>>(Y1, LNY2, n1_w, n1_b, 1024, 4096, LL0);
    G3(1, 8, 32, 1, 4096, 1024, 1024, LNY2, 2048, 1024, LL0, LL0,
       aWq2, 2048, 1024, LL0, LL0, QA2, 2048, 1024, LL0, LL0,
       nullptr, nullptr, 0, 1.f, 1);
    G3(1, 8, 32, 1, 4096, 1024, 1024, LNY2, 2048, 1024, LL0, LL0,
       aWk2, 2048, 1024, LL0, LL0, KA2, 2048, 1024, LL0, LL0,
       nullptr, nullptr, 0, 1.f, 1);
    G3(2, 8, 32, 1, 4096, 1024, 1024, LNY2, 2048, 1024, LL0, LL0,
       aWv2, 2048, 1024, LL0, LL0, VT2, 1024, 512, (long long)1024 * 1024, LL0,
       nullptr, nullptr, 0, 1.f, 1);
    G3(0, 4, 4, 32, 512, 512, 256,
       QA2, 2048, 1024, (long long)512 * 2048, 256,
       KA2, 2048, 1024, (long long)512 * 2048, 256,
       SA, 512, 0, (long long)4 * 512 * 512, (long long)512 * 512,
       nullptr, nullptr, 0, 1.f / 16.f, 4);
    softmax_pair_k<<<16384, 256, 0, stream>>>(SA, P2);
    G3(1, 2, 4, 32, 512, 256, 512,
       P2, 1024, 512, (long long)4 * 512 * 1024, (long long)512 * 1024,
       VT2, 1024, 512, (long long)1024 * 1024, (long long)256 * 1024,
       OA2, 2048, 1024, (long long)512 * 2048, 256,
       nullptr, nullptr, 0, 1.f, 4);
    G3(1, 8, 32, 1, 4096, 1024, 1024, OA2, 2048, 1024, LL0, LL0,
       aWo2, 2048, 1024, LL0, LL0, Y22, 2048, 1024, LL0, LL0,
       aWo_b, Y1, 1024, 1.f, 1);

    // ---- quantize ----
    G3(0, 1, 32, 1, 4096, 64, 1024, Y22, 2048, 1024, LL0, LL0,
       hW2, 2048, 1024, LL0, LL0, G1, 64, 0, LL0, LL0,
       h_b, nullptr, 0, 1.f, 1);
    hc_quant_k<<<4096, 64, 0, stream>>>(G1, h_lnw, h_lnb, HCQ2);

    // ---- decoder (collapsed masked rows) ----
    G3(0, 8, 32, 1, 4096, 1024, 64, HCQ2, 128, 64, LL0, LL0,
       e2dW2, 128, 64, LL0, LL0, DXV, 1024, 0, LL0, LL0,
       nullptr, nullptr, 0, 1.f, 1);
    dxm_k<<<4, 256, 0, stream>>>(mtok, e2d_W, dxm);
    layernorm_k<<<1, 256, 0, stream>>>(dxm, lnm, dn_w, dn_b, 1024, 1, LL0);
    layernorm_pair_k<<<4096, 256, 0, stream>>>(DXV, LNDXV2, dn_w, dn_b, 1024, 4096, LL0);
    projm_k<<<12, 256, 0, stream>>>(lnm, bWq, bWk, bWv, qm, km, vm);
    G1P(0, 8, 32, 1, 4096, 1024, 1024, LNDXV2, 2048, 1024, LL0, LL0,
        bWk2, 2048, 1024, LL0, LL0, Kv, 1024, 0, LL0, LL0,
        nullptr, nullptr, 0, 1.f, 1);
    G1P(0, 8, 32, 1, 4096, 1024, 1024, LNDXV2, 2048, 1024, LL0, LL0,
        bWv2, 2048, 1024, LL0, LL0, Vv, 1024, 0, LL0, LL0,
        nullptr, nullptr, 0, 1.f, 1);
    dec_attn_k<<<dim3(4, 8), 256, 0, stream>>>(Kv, Vv, qm, km, vm, OBm);
    ydm_k<<<32, 256, 0, stream>>>(OBm, bWo, bWo_b, dxm, ydm);
    outm_k<<<64, 256, 0, stream>>>(ydm, dout_W, dout_b, outm);
    bcast_k<<<8192, 256, 0, stream>>>(outm, out);
    #undef G3
    #undef G1P
}

// Round 6
// 1557.149 us; speedup vs baseline: 1.3121x; 1.3121x over previous
//
#include <hip/hip_runtime.h>

// ---------------------------------------------------------------------------
// B=8, N=1024, CIN=2048, HID=1024, HC=64, LV=512, NH_SSD=16, HD=128, DS=64.
// Encoder rows = 4096. Decoder collapsed to 1 row/batch. All large GEMMs:
// split-bf16 MFMA (x3 passes = f32-grade pre-quantizer; x1 post-quantizer).
// SSD intra-chunk = fused MFMA kernel (W in-LDS; X fragments from chan-major
// XCT2 built by an LDS-transpose conv). GEMM K-loop: NON-pipelined (the reg-
// prefetch variant spilled/halved occupancy in round 5 — reverted).
// ---------------------------------------------------------------------------

typedef short bf16x8 __attribute__((ext_vector_type(8)));
typedef float f32x4 __attribute__((ext_vector_type(4)));

__device__ __forceinline__ unsigned short bf16_rne(float f) {
    unsigned u = __float_as_uint(f);
    unsigned r = u + 0x7FFFu + ((u >> 16) & 1u);
    return (unsigned short)(r >> 16);
}
__device__ __forceinline__ float bf16_tof(unsigned short h) {
    return __uint_as_float(((unsigned)h) << 16);
}
// Split pair: row stride 2*width ushorts; hi at [c], lo at [width+c].
__device__ __forceinline__ void store_pair(unsigned short* dst, long long row,
                                           int width, int c, float v) {
    unsigned short hi = bf16_rne(v);
    unsigned short lo = bf16_rne(v - bf16_tof(hi));
    long long base = row * (2LL * width);
    dst[base + c] = hi;
    dst[base + width + c] = lo;
}

// ---------------------------------------------------------------------------
// Reduction helpers (blockDim 256)
// ---------------------------------------------------------------------------
__device__ __forceinline__ float block_sum256(float v) {
    #pragma unroll
    for (int o = 32; o > 0; o >>= 1) v += __shfl_xor(v, o, 64);
    __shared__ float sm[4];
    int w = threadIdx.x >> 6;
    __syncthreads();
    if ((threadIdx.x & 63) == 0) sm[w] = v;
    __syncthreads();
    return sm[0] + sm[1] + sm[2] + sm[3];
}
__device__ __forceinline__ float block_max256(float v) {
    #pragma unroll
    for (int o = 32; o > 0; o >>= 1) v = fmaxf(v, __shfl_xor(v, o, 64));
    __shared__ float smx[4];
    int w = threadIdx.x >> 6;
    __syncthreads();
    if ((threadIdx.x & 63) == 0) smx[w] = v;
    __syncthreads();
    return fmaxf(fmaxf(smx[0], smx[1]), fmaxf(smx[2], smx[3]));
}

// ---------------------------------------------------------------------------
// Split-bf16 MFMA GEMM (non-pipelined K-loop — round-4 proven version).
// C[m,n] = alpha * sum_k A[m,k]*B[n,k] (+bias) (+res)
// NPASS=3: hh+lh+hl (f32-grade). NPASS=1: hh only.
// OUT=0: f32 C. OUT=1: split-pair C. OUT=2: transposed split-pair per 512-row
// batch (b=row>>9 -> C + b*sCb + col*ldc + (row&511), lo at +cLo).
// ---------------------------------------------------------------------------
template<int NPASS, int OUT>
__global__ __launch_bounds__(256, 2) void gemm_bf16_k(
    int M, int N, int K,
    const unsigned short* __restrict__ A2, int lda2, int aLo, long long sAb, long long sAh,
    const unsigned short* __restrict__ B2, int ldb2, int bLo, long long sBb, long long sBh,
    void* __restrict__ Cv, int ldc, int cLo, long long sCb, long long sCh,
    const float* __restrict__ bias, const float* __restrict__ res, int ldr,
    float alpha, int nh)
{
    __shared__ unsigned short Ah[128 * 40];
    __shared__ unsigned short Bh[128 * 40];
    __shared__ unsigned short Al[128 * 40];
    __shared__ unsigned short Bl[128 * 40];

    const int z  = blockIdx.z;
    const int bb = z / nh, hh = z - bb * nh;
    A2 += bb * sAb + hh * sAh;
    B2 += bb * sBb + hh * sBh;

    const int t    = threadIdx.x;
    const int m0   = blockIdx.y * 128;
    const int n0   = blockIdx.x * 128;
    const int lane = t & 63, wave = t >> 6;
    const int wm   = (wave >> 1) * 64, wn = (wave & 1) * 64;
    const int lr   = lane & 15, quad = lane >> 4;

    f32x4 acc[4][4];
    #pragma unroll
    for (int i = 0; i < 4; ++i)
        #pragma unroll
        for (int j = 0; j < 4; ++j) acc[i][j] = (f32x4){0.f, 0.f, 0.f, 0.f};

    const int srow = t >> 2;
    const int scol = (t & 3) * 8;

    for (int k0 = 0; k0 < K; k0 += 32) {
        __syncthreads();
        #pragma unroll
        for (int half = 0; half < 2; ++half) {
            int r = srow + half * 64;
            const unsigned short* pA = A2 + (long long)(m0 + r) * lda2 + k0 + scol;
            *(uint4*)&Ah[r * 40 + scol] = *(const uint4*)pA;
            if (NPASS == 3)
                *(uint4*)&Al[r * 40 + scol] = *(const uint4*)(pA + aLo);
            int rb = n0 + r;
            uint4 vh = {0u, 0u, 0u, 0u}, vl = {0u, 0u, 0u, 0u};
            if (rb < N) {
                const unsigned short* pB = B2 + (long long)rb * ldb2 + k0 + scol;
                vh = *(const uint4*)pB;
                if (NPASS == 3) vl = *(const uint4*)(pB + bLo);
            }
            *(uint4*)&Bh[r * 40 + scol] = vh;
            if (NPASS == 3) *(uint4*)&Bl[r * 40 + scol] = vl;
        }
        __syncthreads();

        bf16x8 ah[4], bh[4], al[4], bl[4];
        #pragma unroll
        for (int i = 0; i < 4; ++i) {
            int ra = (wm + i * 16 + lr) * 40 + quad * 8;
            int rb = (wn + i * 16 + lr) * 40 + quad * 8;
            ah[i] = *(const bf16x8*)&Ah[ra];
            bh[i] = *(const bf16x8*)&Bh[rb];
            if (NPASS == 3) {
                al[i] = *(const bf16x8*)&Al[ra];
                bl[i] = *(const bf16x8*)&Bl[rb];
            }
        }
        #pragma unroll
        for (int mi = 0; mi < 4; ++mi)
            #pragma unroll
            for (int ni = 0; ni < 4; ++ni) {
                acc[mi][ni] = __builtin_amdgcn_mfma_f32_16x16x32_bf16(
                    ah[mi], bh[ni], acc[mi][ni], 0, 0, 0);
                if (NPASS == 3) {
                    acc[mi][ni] = __builtin_amdgcn_mfma_f32_16x16x32_bf16(
                        al[mi], bh[ni], acc[mi][ni], 0, 0, 0);
                    acc[mi][ni] = __builtin_amdgcn_mfma_f32_16x16x32_bf16(
                        ah[mi], bl[ni], acc[mi][ni], 0, 0, 0);
                }
            }
    }

    // D layout: col = lane&15, row = quad*4 + r
    if (OUT == 0) {
        float* C = (float*)Cv + bb * sCb + hh * sCh;
        #pragma unroll
        for (int mi = 0; mi < 4; ++mi)
            #pragma unroll
            for (int ni = 0; ni < 4; ++ni) {
                int col = n0 + wn + ni * 16 + lr;
                if (col >= N) continue;
                float bv = bias ? bias[col] : 0.f;
                #pragma unroll
                for (int r = 0; r < 4; ++r) {
                    int row = m0 + wm + mi * 16 + quad * 4 + r;
                    float v = alpha * acc[mi][ni][r] + bv;
                    if (res) v += res[(long long)row * ldr + col];
                    C[(long long)row * ldc + col] = v;
                }
            }
    } else if (OUT == 1) {
        unsigned short* C = (unsigned short*)Cv + bb * sCb + hh * sCh;
        #pragma unroll
        for (int mi = 0; mi < 4; ++mi)
            #pragma unroll
            for (int ni = 0; ni < 4; ++ni) {
                int col = n0 + wn + ni * 16 + lr;
                if (col >= N) continue;
                float bv = bias ? bias[col] : 0.f;
                #pragma unroll
                for (int r = 0; r < 4; ++r) {
                    int row = m0 + wm + mi * 16 + quad * 4 + r;
                    float v = alpha * acc[mi][ni][r] + bv;
                    if (res) v += res[(long long)row * ldr + col];
                    unsigned short hi = bf16_rne(v);
                    unsigned short lo = bf16_rne(v - bf16_tof(hi));
                    long long p = (long long)row * ldc + col;
                    C[p] = hi;
                    C[p + cLo] = lo;
                }
            }
    } else {  // OUT == 2: transposed pairs per 512-row batch
        unsigned short* C = (unsigned short*)Cv;
        #pragma unroll
        for (int mi = 0; mi < 4; ++mi)
            #pragma unroll
            for (int ni = 0; ni < 4; ++ni) {
                int col = n0 + wn + ni * 16 + lr;
                if (col >= N) continue;
                int row0 = m0 + wm + mi * 16 + quad * 4;
                int b = row0 >> 9, seq0 = row0 & 511;
                ushort4 h4, l4;
                unsigned short* hp = (unsigned short*)&h4;
                unsigned short* lp = (unsigned short*)&l4;
                #pragma unroll
                for (int r = 0; r < 4; ++r) {
                    float v = acc[mi][ni][r];
                    unsigned short hi = bf16_rne(v);
                    hp[r] = hi;
                    lp[r] = bf16_rne(v - bf16_tof(hi));
                }
                long long p = b * sCb + (long long)col * ldc + seq0;
                *(ushort4*)&C[p] = h4;
                *(ushort4*)&C[p + cLo] = l4;
            }
    }
}

// ---------------------------------------------------------------------------
// Fused SSD intra-chunk MFMA kernel.
// Per (b,h): Y[l,p] = sum_{s<=l} W[l,s]*XC[s,p], W = G*exp(cAl-cAs)*dt[s].
// W computed into LDS as split-bf16 pairs; X fragments from chan-major pairs
// XCT2[b][chan][seq] (hi at +0, lo at +512). Epilogue reads XC2 (seq-major
// pairs) and Z (f32, seq-major) — all coalesced. 3-pass split precision.
// grid (4 l-tiles, 16 h, 8 b), block 256.
// ---------------------------------------------------------------------------
__global__ __launch_bounds__(256, 2) void ssd_mfma_k(
    const float* __restrict__ G, const float* __restrict__ CUMA,
    const float* __restrict__ DT, const unsigned short* __restrict__ XCT2,
    const unsigned short* __restrict__ XC2, const float* __restrict__ Z,
    const float* __restrict__ Dv, unsigned short* __restrict__ YS2)
{
    __shared__ unsigned short Ah[128 * 40];
    __shared__ unsigned short Al[128 * 40];
    const int mt = blockIdx.x, h = blockIdx.y, b = blockIdx.z;
    const int t = threadIdx.x;
    const int lane = t & 63, wave = t >> 6;
    const int wm = (wave >> 1) * 64, wn = (wave & 1) * 64;
    const int lr = lane & 15, quad = lane >> 4;
    const int m0 = mt * 128;

    const int wl = t >> 1;
    const int ws0 = (t & 1) * 16;
    const int lglob = m0 + wl;
    const float* cbase = CUMA + (b * 16 + h) * 512;
    const float cAl = cbase[lglob];
    const float* gbase = G + ((long long)(b * 512 + lglob)) * 512;
    const float* dtb = DT + (long long)b * 512 * 16 + h;

    f32x4 acc[4][4];
    #pragma unroll
    for (int i = 0; i < 4; ++i)
        #pragma unroll
        for (int j = 0; j < 4; ++j) acc[i][j] = (f32x4){0.f, 0.f, 0.f, 0.f};

    const unsigned short* XB = XCT2 + (long long)b * 2097152 + (long long)(h * 128) * 1024;

    const int kend = (mt + 1) * 128;
    for (int k0 = 0; k0 < kend; k0 += 32) {
        __syncthreads();
        #pragma unroll
        for (int jj = 0; jj < 4; ++jj) {
            int s0 = k0 + ws0 + jj * 4;
            float4 g = *(const float4*)(gbase + s0);
            float gv[4] = {g.x, g.y, g.z, g.w};
            #pragma unroll
            for (int e = 0; e < 4; ++e) {
                int sg = s0 + e;
                float w = 0.f;
                if (sg <= lglob)
                    w = gv[e] * expf(cAl - cbase[sg]) * dtb[(long long)sg * 16];
                unsigned short hi = bf16_rne(w);
                unsigned short lo = bf16_rne(w - bf16_tof(hi));
                Ah[wl * 40 + ws0 + jj * 4 + e] = hi;
                Al[wl * 40 + ws0 + jj * 4 + e] = lo;
            }
        }
        __syncthreads();
        bf16x8 ah[4], al[4];
        #pragma unroll
        for (int i = 0; i < 4; ++i) {
            int ra = (wm + i * 16 + lr) * 40 + quad * 8;
            ah[i] = *(const bf16x8*)&Ah[ra];
            al[i] = *(const bf16x8*)&Al[ra];
        }
        #pragma unroll
        for (int ni = 0; ni < 4; ++ni) {
            const unsigned short* pB = XB + (long long)(wn + ni * 16 + lr) * 1024 + k0 + quad * 8;
            bf16x8 bh = *(const bf16x8*)pB;
            bf16x8 bl = *(const bf16x8*)(pB + 512);
            #pragma unroll
            for (int mi = 0; mi < 4; ++mi) {
                acc[mi][ni] = __builtin_amdgcn_mfma_f32_16x16x32_bf16(
                    ah[mi], bh, acc[mi][ni], 0, 0, 0);
                acc[mi][ni] = __builtin_amdgcn_mfma_f32_16x16x32_bf16(
                    al[mi], bh, acc[mi][ni], 0, 0, 0);
                acc[mi][ni] = __builtin_amdgcn_mfma_f32_16x16x32_bf16(
                    ah[mi], bl, acc[mi][ni], 0, 0, 0);
            }
        }
    }

    const float Dh = Dv[h];
    #pragma unroll
    for (int mi = 0; mi < 4; ++mi)
        #pragma unroll
        for (int ni = 0; ni < 4; ++ni) {
            int chan = h * 128 + wn + ni * 16 + lr;
            int row0 = m0 + wm + mi * 16 + quad * 4;
            #pragma unroll
            for (int r = 0; r < 4; ++r) {
                long long row = (long long)(b * 512 + row0 + r);
                float xc = bf16_tof(XC2[row * 4096 + chan]) +
                           bf16_tof(XC2[row * 4096 + 2048 + chan]);
                float zz = Z[row * 2048 + chan];
                float y = (acc[mi][ni][r] + xc * Dh) * (zz / (1.f + expf(-zz)));
                store_pair(YS2, row, 2048, chan, y);
            }
        }
}

// ---------------------------------------------------------------------------
// Tiled f32 GEMM (only for the small batched G = Cm @ Bm^T)
// ---------------------------------------------------------------------------
__global__ __launch_bounds__(256) void gemm_f32_k(
    int M, int N, int K,
    const float* __restrict__ A, int lda, long long sAb,
    const float* __restrict__ B, int ldb, long long sBb,
    float* __restrict__ C, int ldc, long long sCb)
{
    __shared__ float As[32][132];
    __shared__ float Bs[32][132];
    const int z = blockIdx.z;
    A += z * sAb; B += z * sBb; C += z * sCb;
    const int n0 = blockIdx.x * 128;
    const int m0 = blockIdx.y * 128;
    const int t  = threadIdx.x;
    const int tx = t & 15, ty = t >> 4;

    float acc[4][16];
    #pragma unroll
    for (int a = 0; a < 4; ++a)
        #pragma unroll
        for (int q = 0; q < 16; ++q) acc[a][q] = 0.f;

    const int ka = (t & 7) << 2;
    const int ra = t >> 3;

    for (int k0 = 0; k0 < K; k0 += 32) {
        __syncthreads();
        #pragma unroll
        for (int i = 0; i < 4; ++i) {
            int row = m0 + ra + i * 32;
            float4 v = *(const float4*)(A + (long long)row * lda + (k0 + ka));
            As[ka + 0][ra + i * 32] = v.x;
            As[ka + 1][ra + i * 32] = v.y;
            As[ka + 2][ra + i * 32] = v.z;
            As[ka + 3][ra + i * 32] = v.w;
            int rowb = n0 + ra + i * 32;
            float4 w = *(const float4*)(B + (long long)rowb * ldb + (k0 + ka));
            Bs[ka + 0][ra + i * 32] = w.x;
            Bs[ka + 1][ra + i * 32] = w.y;
            Bs[ka + 2][ra + i * 32] = w.z;
            Bs[ka + 3][ra + i * 32] = w.w;
        }
        __syncthreads();
        #pragma unroll
        for (int kk = 0; kk < 32; ++kk) {
            float a[8], bm[8];
            *(float4*)&a[0]  = *(const float4*)&As[kk][ty * 4];
            *(float4*)&a[4]  = *(const float4*)&As[kk][64 + ty * 4];
            *(float4*)&bm[0] = *(const float4*)&Bs[kk][tx * 4];
            *(float4*)&bm[4] = *(const float4*)&Bs[kk][64 + tx * 4];
            #pragma unroll
            for (int ri = 0; ri < 2; ++ri)
                #pragma unroll
                for (int ci = 0; ci < 2; ++ci)
                    #pragma unroll
                    for (int i = 0; i < 4; ++i)
                        #pragma unroll
                        for (int j = 0; j < 4; ++j)
                            acc[ri * 2 + ci][i * 4 + j] =
                                fmaf(a[ri * 4 + i], bm[ci * 4 + j], acc[ri * 2 + ci][i * 4 + j]);
        }
    }
    #pragma unroll
    for (int ri = 0; ri < 2; ++ri)
        #pragma unroll
        for (int ci = 0; ci < 2; ++ci) {
            int colb = n0 + ci * 64 + tx * 4;
            #pragma unroll
            for (int i = 0; i < 4; ++i) {
                int row = m0 + ri * 64 + ty * 4 + i;
                *(float4*)(C + (long long)row * ldc + colb) =
                    *(float4*)&acc[ri * 2 + ci][i * 4];
            }
        }
}

// ---------------------------------------------------------------------------
// Elementwise / norm kernels
// ---------------------------------------------------------------------------
__global__ __launch_bounds__(256) void pairify_k(
    const float* __restrict__ src, unsigned short* __restrict__ dst,
    int k_log2, long long n)
{
    long long idx = (long long)blockIdx.x * 256 + threadIdx.x;
    if (idx >= n) return;
    long long r = idx >> k_log2;
    int c = (int)(idx & ((1 << k_log2) - 1));
    store_pair(dst, r, 1 << k_log2, c, src[idx]);
}

__global__ __launch_bounds__(256) void layernorm_k(
    const float* __restrict__ in, float* __restrict__ out,
    const float* __restrict__ w, const float* __restrict__ b,
    int width, int rows_per_b, long long in_bstride)
{
    long long r = blockIdx.x;
    const float* x = in + (r / rows_per_b) * in_bstride + (r % rows_per_b) * (long long)width;
    int t = threadIdx.x;
    float s = 0.f;
    for (int c = t; c < width; c += 256) s += x[c];
    s = block_sum256(s);
    float m = s / (float)width;
    float vs = 0.f;
    for (int c = t; c < width; c += 256) { float d = x[c] - m; vs += d * d; }
    vs = block_sum256(vs);
    float rs = 1.f / sqrtf(vs / (float)width + 1e-5f);
    float* o = out + r * (long long)width;
    for (int c = t; c < width; c += 256) o[c] = (x[c] - m) * rs * w[c] + b[c];
}

__global__ __launch_bounds__(256) void layernorm_pair_k(
    const float* __restrict__ in, unsigned short* __restrict__ out2,
    const float* __restrict__ w, const float* __restrict__ b,
    int width, int rows_per_b, long long in_bstride)
{
    long long r = blockIdx.x;
    const float* x = in + (r / rows_per_b) * in_bstride + (r % rows_per_b) * (long long)width;
    int t = threadIdx.x;
    float s = 0.f;
    for (int c = t; c < width; c += 256) s += x[c];
    s = block_sum256(s);
    float m = s / (float)width;
    float vs = 0.f;
    for (int c = t; c < width; c += 256) { float d = x[c] - m; vs += d * d; }
    vs = block_sum256(vs);
    float rs = 1.f / sqrtf(vs / (float)width + 1e-5f);
    for (int c = t; c < width; c += 256)
        store_pair(out2, r, width, c, (x[c] - m) * rs * w[c] + b[c]);
}

__global__ __launch_bounds__(256) void rmsnorm_pair_k(
    const float* __restrict__ in, unsigned short* __restrict__ out2,
    const float* __restrict__ w, int width)
{
    long long r = blockIdx.x;
    const float* x = in + r * (long long)width;
    int t = threadIdx.x;
    float s = 0.f;
    for (int c = t; c < width; c += 256) { float v = x[c]; s += v * v; }
    s = block_sum256(s);
    float rs = 1.f / sqrtf(s / (float)width + 1e-5f);
    for (int c = t; c < width; c += 256)
        store_pair(out2, r, width, c, x[c] * rs * w[c]);
}

// Softmax over 512-wide rows, f32 in -> split-pair out IN-PLACE (same bytes).
__global__ __launch_bounds__(256) void softmax_pair_k(float* __restrict__ S,
                                                      unsigned short* __restrict__ P2)
{
    long long r = blockIdx.x;
    float* x = S + r * 512;
    unsigned short* p = P2 + r * 1024;
    int t = threadIdx.x;
    float v0 = x[t], v1 = x[t + 256];
    float mx = block_max256(fmaxf(v0, v1));
    v0 = expf(v0 - mx); v1 = expf(v1 - mx);
    float sum = block_sum256(v0 + v1);
    float inv = 1.f / sum;
    v0 *= inv; v1 *= inv;
    __syncthreads();
    unsigned short h0 = bf16_rne(v0);
    p[t] = h0;       p[512 + t] = bf16_rne(v0 - bf16_tof(h0));
    unsigned short h1 = bf16_rne(v1);
    p[t + 256] = h1; p[512 + t + 256] = bf16_rne(v1 - bf16_tof(h1));
}

// Causal grouped conv with LDS-tile transpose: writes seq-major pairs XC2
// AND chan-major pairs XCT2, both coalesced.
// grid (32 chan-tiles, 8 seq-tiles, 8 b), block 256; tile = 64 seq x 64 chan.
__global__ __launch_bounds__(256) void conv_k(
    const float* __restrict__ XS, const float* __restrict__ W,
    unsigned short* __restrict__ XC2, unsigned short* __restrict__ XCT2)
{
    __shared__ float tile[64][65];   // [seq_local][chan_local]; col reads conflict-free
    const int o0  = blockIdx.x * 64;
    const int tt0 = blockIdx.y * 64;
    const int b   = blockIdx.z;
    const int t   = threadIdx.x;

    // compute phase: thread owns chan o, 16 seq rows
    const int o  = o0 + (t & 63);
    const int g2 = (o >> 1) << 1;
    const float* Wo = W + o * 8;
    float w0 = Wo[0], w1 = Wo[1], w2 = Wo[2], w3 = Wo[3];
    float w4 = Wo[4], w5 = Wo[5], w6 = Wo[6], w7 = Wo[7];
    #pragma unroll
    for (int i = 0; i < 16; ++i) {
        int sl = (t >> 6) + 4 * i;
        int tt = tt0 + sl;
        const float* xb = XS + ((long long)(b * 512 + tt)) * 2048 + g2;
        float acc = w3 * xb[0] + w7 * xb[1];
        if (tt >= 1) acc += w2 * xb[-2048] + w6 * xb[-2047];
        if (tt >= 2) acc += w1 * xb[-4096] + w5 * xb[-4095];
        if (tt >= 3) acc += w0 * xb[-6144] + w4 * xb[-6143];
        tile[sl][t & 63] = acc;
    }
    __syncthreads();
    // XC2 (seq-major): per wave, one row, 64 consecutive ushorts
    #pragma unroll
    for (int i = 0; i < 16; ++i) {
        int idx = t + 256 * i;
        int sl = idx >> 6, ol = idx & 63;
        float v = tile[sl][ol];
        unsigned short hi = bf16_rne(v);
        unsigned short lo = bf16_rne(v - bf16_tof(hi));
        long long row = (long long)(b * 512 + tt0 + sl);
        XC2[row * 4096 + o0 + ol] = hi;
        XC2[row * 4096 + 2048 + o0 + ol] = lo;
    }
    // XCT2 (chan-major): per wave, one chan row, 64 consecutive seq ushorts
    #pragma unroll
    for (int i = 0; i < 16; ++i) {
        int idx = t + 256 * i;
        int cl = idx >> 6, s = idx & 63;
        float v = tile[s][cl];
        unsigned short hi = bf16_rne(v);
        unsigned short lo = bf16_rne(v - bf16_tof(hi));
        long long tb = (long long)b * 2097152 + (long long)(o0 + cl) * 1024 + tt0 + s;
        XCT2[tb] = hi;
        XCT2[tb + 512] = lo;
    }
}

__global__ __launch_bounds__(256) void dt_k(
    const float* __restrict__ dtBC, const float* __restrict__ dt_bias, float* __restrict__ DT)
{
    int idx = blockIdx.x * 256 + threadIdx.x;
    int r = idx >> 4, h = idx & 15;
    float xv = dtBC[r * 144 + h] + dt_bias[h];
    DT[idx] = (xv > 20.f) ? xv : log1pf(expf(xv));
}

__global__ __launch_bounds__(64) void cuma_k(
    const float* __restrict__ DT, const float* __restrict__ A_log, float* __restrict__ CUMA)
{
    int h = blockIdx.x, b = blockIdx.y;
    int ln = threadIdx.x;
    float Ah = -expf(A_log[h]);
    float v[8];
    float run = 0.f;
    #pragma unroll
    for (int i = 0; i < 8; ++i) {
        run += Ah * DT[((b * 512) + (ln * 8 + i)) * 16 + h];
        v[i] = run;
    }
    float tot = run;
    float sc = tot;
    #pragma unroll
    for (int o = 1; o <= 32; o <<= 1) {
        float u = __shfl_up(sc, o, 64);
        if (ln >= o) sc += u;
    }
    float excl = sc - tot;
    #pragma unroll
    for (int i = 0; i < 8; ++i)
        CUMA[(b * 16 + h) * 512 + ln * 8 + i] = excl + v[i];
}

// hc = LayerNorm64(G1) -> {-1,+1} as split pairs (lo = 0)
__global__ __launch_bounds__(64) void hc_quant_k(
    const float* __restrict__ G1, const float* __restrict__ w,
    const float* __restrict__ b, unsigned short* __restrict__ HCQ2)
{
    int r = blockIdx.x, ln = threadIdx.x;
    float v = G1[r * 64 + ln];
    float s = v;
    #pragma unroll
    for (int o = 32; o > 0; o >>= 1) s += __shfl_xor(s, o, 64);
    float m = s * (1.f / 64.f);
    float d = v - m;
    float vs = d * d;
    #pragma unroll
    for (int o = 32; o > 0; o >>= 1) vs += __shfl_xor(vs, o, 64);
    vs *= (1.f / 64.f);
    float hc = d * (1.f / sqrtf(vs + 1e-5f)) * w[ln] + b[ln];
    HCQ2[r * 128 + ln] = (hc > 0.f) ? 0x3F80 : 0xBF80;
    HCQ2[r * 128 + 64 + ln] = 0;
}

__global__ __launch_bounds__(256) void dxm_k(
    const float* __restrict__ mtok, const float* __restrict__ e2d, float* __restrict__ dxm)
{
    int c = blockIdx.x * 256 + threadIdx.x;
    float acc = 0.f;
    #pragma unroll
    for (int j = 0; j < 64; ++j) acc = fmaf(mtok[j], e2d[c * 64 + j], acc);
    dxm[c] = acc;
}

__global__ __launch_bounds__(256) void projm_k(
    const float* __restrict__ lnm,
    const float* __restrict__ bWq, const float* __restrict__ bWk, const float* __restrict__ bWv,
    float* __restrict__ qm, float* __restrict__ km, float* __restrict__ vm)
{
    int idx = blockIdx.x * 256 + threadIdx.x;
    int sel = idx >> 10, c = idx & 1023;
    const float* W = (sel == 0) ? bWq : (sel == 1) ? bWk : bWv;
    float* O = (sel == 0) ? qm : (sel == 1) ? km : vm;
    const float* wr = W + (long long)c * 1024;
    float acc = 0.f;
    for (int j = 0; j < 1024; j += 4) {
        float4 a = *(const float4*)(lnm + j);
        float4 w4 = *(const float4*)(wr + j);
        acc = fmaf(a.x, w4.x, fmaf(a.y, w4.y, fmaf(a.z, w4.z, fmaf(a.w, w4.w, acc))));
    }
    O[c] = acc;
}

// Collapsed decoder attention: 1 query/(b,h); keys = 512 visible + mask key x512.
__global__ __launch_bounds__(256) void dec_attn_k(
    const float* __restrict__ Kv, const float* __restrict__ Vv,
    const float* __restrict__ qm, const float* __restrict__ km,
    const float* __restrict__ vm, float* __restrict__ OBm)
{
    int h = blockIdx.x, b = blockIdx.y;
    int t = threadIdx.x;
    __shared__ __align__(16) float qs[256];
    __shared__ __align__(16) float ps[512];
    qs[t] = qm[h * 256 + t];
    __syncthreads();
    float s[2];
    #pragma unroll
    for (int i = 0; i < 2; ++i) {
        int r = t + i * 256;
        const float* kr = Kv + ((long long)(b * 512 + r)) * 1024 + h * 256;
        float acc = 0.f;
        for (int c = 0; c < 256; c += 4) {
            float4 k4 = *(const float4*)(kr + c);
            float4 q4 = *(const float4*)(qs + c);
            acc = fmaf(k4.x, q4.x, fmaf(k4.y, q4.y, fmaf(k4.z, q4.z, fmaf(k4.w, q4.w, acc))));
        }
        s[i] = acc * (1.f / 16.f);
    }
    float accm = 0.f;
    for (int c = 0; c < 256; c += 4) {
        float4 k4 = *(const float4*)(km + h * 256 + c);
        float4 q4 = *(const float4*)(qs + c);
        accm = fmaf(k4.x, q4.x, fmaf(k4.y, q4.y, fmaf(k4.z, q4.z, fmaf(k4.w, q4.w, accm))));
    }
    float smv = accm * (1.f / 16.f);
    float mx = block_max256(fmaxf(fmaxf(s[0], s[1]), smv));
    float p0 = expf(s[0] - mx), p1 = expf(s[1] - mx);
    ps[t] = p0; ps[t + 256] = p1;
    float pm = expf(smv - mx) * 512.f;
    float sum = block_sum256(p0 + p1) + pm;
    float inv = 1.f / sum;
    __syncthreads();
    float o = pm * vm[h * 256 + t];
    const float* vcol = Vv + (long long)b * 512 * 1024 + h * 256 + t;
    for (int j = 0; j < 512; ++j)
        o = fmaf(ps[j], vcol[(long long)j * 1024], o);
    OBm[b * 1024 + h * 256 + t] = o * inv;
}

__global__ __launch_bounds__(256) void ydm_k(
    const float* __restrict__ OBm, const float* __restrict__ bWo,
    const float* __restrict__ bWo_b, const float* __restrict__ dxm,
    float* __restrict__ ydm)
{
    int idx = blockIdx.x * 256 + threadIdx.x;
    int b = idx >> 10, c = idx & 1023;
    const float* ar = OBm + b * 1024;
    const float* wr = bWo + (long long)c * 1024;
    float acc = 0.f;
    for (int j = 0; j < 1024; j += 4) {
        float4 a = *(const float4*)(ar + j);
        float4 w4 = *(const float4*)(wr + j);
        acc = fmaf(a.x, w4.x, fmaf(a.y, w4.y, fmaf(a.z, w4.z, fmaf(a.w, w4.w, acc))));
    }
    ydm[idx] = acc + bWo_b[c] + dxm[c];
}

__global__ __launch_bounds__(256) void outm_k(
    const float* __restrict__ ydm, const float* __restrict__ dout_W,
    const float* __restrict__ dout_b, float* __restrict__ outm)
{
    int idx = blockIdx.x * 256 + threadIdx.x;
    int b = idx >> 11, c = idx & 2047;
    const float* ar = ydm + b * 1024;
    const float* wr = dout_W + (long long)c * 1024;
    float acc = 0.f;
    for (int j = 0; j < 1024; j += 4) {
        float4 a = *(const float4*)(ar + j);
        float4 w4 = *(const float4*)(wr + j);
        acc = fmaf(a.x, w4.x, fmaf(a.y, w4.y, fmaf(a.z, w4.z, fmaf(a.w, w4.w, acc))));
    }
    outm[idx] = acc + dout_b[c];
}

__global__ __launch_bounds__(256) void bcast_k(
    const float* __restrict__ outm, float* __restrict__ out)
{
    int idx = blockIdx.x * 256 + threadIdx.x;
    int c4 = idx & 511;
    int b = idx >> 18;
    ((float4*)out)[idx] = ((const float4*)outm)[b * 512 + c4];
}

// ---------------------------------------------------------------------------
// Host-side launcher
// ---------------------------------------------------------------------------
static inline void pairify(hipStream_t s, const float* src, unsigned short* dst,
                           int k_log2, long long n)
{
    pairify_k<<<(int)((n + 255) / 256), 256, 0, s>>>(src, dst, k_log2, n);
}

extern "C" void kernel_launch(void* const* d_in, const int* in_sizes, int n_in,
                              void* d_out, int out_size, void* d_ws, size_t ws_size,
                              hipStream_t stream)
{
    const float* x       = (const float*)d_in[0];
    const float* ln0_w   = (const float*)d_in[1];
    const float* ln0_b   = (const float*)d_in[2];
    const float* in_W    = (const float*)d_in[3];
    const float* rms_w   = (const float*)d_in[4];
    const float* exp_W   = (const float*)d_in[5];
    const float* conv_W  = (const float*)d_in[6];
    const float* xproj_W = (const float*)d_in[7];
    const float* dt_bias = (const float*)d_in[8];
    const float* A_log   = (const float*)d_in[9];
    const float* Dv      = (const float*)d_in[10];
    const float* outp_W  = (const float*)d_in[11];
    const float* outp_b  = (const float*)d_in[12];
    const float* n1_w    = (const float*)d_in[13];
    const float* n1_b    = (const float*)d_in[14];
    const float* aWq     = (const float*)d_in[15];
    const float* aWk     = (const float*)d_in[16];
    const float* aWv     = (const float*)d_in[17];
    const float* aWo     = (const float*)d_in[18];
    const float* aWo_b   = (const float*)d_in[19];
    const float* h_W     = (const float*)d_in[20];
    const float* h_b     = (const float*)d_in[21];
    const float* h_lnw   = (const float*)d_in[22];
    const float* h_lnb   = (const float*)d_in[23];
    const float* mtok    = (const float*)d_in[24];
    const float* e2d_W   = (const float*)d_in[25];
    const float* dn_w    = (const float*)d_in[26];
    const float* dn_b    = (const float*)d_in[27];
    const float* bWq     = (const float*)d_in[28];
    const float* bWk     = (const float*)d_in[29];
    const float* bWv     = (const float*)d_in[30];
    const float* bWo     = (const float*)d_in[31];
    const float* bWo_b   = (const float*)d_in[32];
    const float* dout_W  = (const float*)d_in[33];
    const float* dout_b  = (const float*)d_in[34];

    float* ws  = (float*)d_ws;
    float* out = (float*)d_out;

    // ---- slots (float offsets) ----
    // S1 8.39M: XV2 | exp_W2 | XCT2 | SA/P2 | Kv+Vv
    // S2 8.39M: in_W2 | XS | YS2
    // S3 8.39M: XC2 | (outp_W2 after ssd) | DXV + LNDXV2
    // S4 8.39M: Z f32 | aW{q,k,v,o}2 + bW{k,v}2
    // S5 4.19M: T | QA2 | Y22      S6: HR2 | Y1      S7: LNY2 | OA2
    // S8 4.19M: KA2                S9: VT2           SP: small pool
    float* S1 = ws;
    float* S2 = ws + 8388608;
    float* S3 = ws + 16777216;
    float* S4 = ws + 25165824;
    float* S5 = ws + 33554432;
    float* S6 = ws + 37748736;
    float* S7 = ws + 41943040;
    float* S8 = ws + 46137344;
    float* S9 = ws + 50331648;
    float* SP = ws + 54525952;

    unsigned short* XV2     = (unsigned short*)S1;
    unsigned short* exp_W2  = (unsigned short*)S1;
    unsigned short* XCT2    = (unsigned short*)S1;
    float*          SA      = S1;
    unsigned short* P2      = (unsigned short*)S1;
    float*          Kv      = S1;
    float*          Vv      = S1 + 4194304;
    unsigned short* in_W2   = (unsigned short*)S2;
    float*          XS      = S2;
    unsigned short* YS2     = (unsigned short*)S2;
    unsigned short* XC2     = (unsigned short*)S3;
    unsigned short* outp_W2 = (unsigned short*)S3;
    float*          DXV     = S3;
    unsigned short* LNDXV2  = (unsigned short*)(S3 + 4194304);
    float*          Z       = S4;
    unsigned short* aWq2    = (unsigned short*)S4;
    unsigned short* aWk2    = (unsigned short*)S4 + 2097152;
    unsigned short* aWv2    = (unsigned short*)S4 + 4194304;
    unsigned short* aWo2    = (unsigned short*)S4 + 6291456;
    unsigned short* bWk2    = (unsigned short*)S4 + 8388608;
    unsigned short* bWv2    = (unsigned short*)S4 + 10485760;
    float*          T       = S5;
    unsigned short* QA2     = (unsigned short*)S5;
    unsigned short* Y22     = (unsigned short*)S5;
    unsigned short* HR2     = (unsigned short*)S6;
    float*          Y1      = S6;
    unsigned short* LNY2    = (unsigned short*)S7;
    unsigned short* OA2     = (unsigned short*)S7;
    unsigned short* KA2     = (unsigned short*)S8;
    unsigned short* VT2     = (unsigned short*)S9;

    float* dtBC = SP;                     // 589,824
    float* DT   = SP + 589824;            // 65,536
    float* CUMA = SP + 655360;            // 65,536
    float* G    = SP + 720896;            // 2,097,152  [live: G GEMM -> ssd]
    unsigned short* xprojW2 = (unsigned short*)(SP + 2818048);  // 294,912 fl
    unsigned short* hW2     = (unsigned short*)(SP + 3112960);  // 65,536 fl
    unsigned short* e2dW2   = (unsigned short*)(SP + 3178496);  // 65,536 fl
    float* G1   = SP + 720896;            // alias over dead G
    unsigned short* HCQ2 = (unsigned short*)(SP + 983040);      // 262,144 fl
    float* dxm  = SP + 1245184;
    float* lnm  = SP + 1246208;
    float* qm   = SP + 1247232;
    float* km   = SP + 1248256;
    float* vm   = SP + 1249280;
    float* OBm  = SP + 1250304;
    float* ydm  = SP + 1258496;
    float* outm = SP + 1266688;

    const long long LL0 = 0;
    #define G3(OUTM, GX, GY, GZ, ...) \
        gemm_bf16_k<3, OUTM><<<dim3(GX, GY, GZ), 256, 0, stream>>>(__VA_ARGS__)
    #define G1P(OUTM, GX, GY, GZ, ...) \
        gemm_bf16_k<1, OUTM><<<dim3(GX, GY, GZ), 256, 0, stream>>>(__VA_ARGS__)

    // ---- weight prep (phase A) ----
    pairify(stream, in_W,    in_W2,   11, 1024LL * 2048);
    pairify(stream, xproj_W, xprojW2, 11, 144LL * 2048);
    pairify(stream, h_W,     hW2,     10, 64LL * 1024);
    pairify(stream, e2d_W,   e2dW2,    6, 1024LL * 64);

    // ---- encoder trunk ----
    layernorm_pair_k<<<4096, 256, 0, stream>>>(x, XV2, ln0_w, ln0_b, 2048, 512,
                                               (long long)1024 * 2048);
    G3(0, 8, 32, 1, 4096, 1024, 2048, XV2, 4096, 2048, LL0, LL0,
       in_W2, 4096, 2048, LL0, LL0, T, 1024, 0, LL0, LL0,
       nullptr, nullptr, 0, 1.f, 1);
    pairify(stream, exp_W, exp_W2, 10, 4096LL * 1024);   // S1 (XV2 dead)
    rmsnorm_pair_k<<<4096, 256, 0, stream>>>(T, HR2, rms_w, 1024);
    G3(0, 16, 32, 1, 4096, 2048, 1024, HR2, 2048, 1024, LL0, LL0,
       exp_W2, 2048, 1024, LL0, LL0, XS, 2048, 0, LL0, LL0,
       nullptr, nullptr, 0, 1.f, 1);
    G3(0, 16, 32, 1, 4096, 2048, 1024, HR2, 2048, 1024, LL0, LL0,
       exp_W2 + 2048LL * 2048, 2048, 1024, LL0, LL0, Z, 2048, 0, LL0, LL0,
       nullptr, nullptr, 0, 1.f, 1);
    // conv: XS -> XC2 (seq-major) + XCT2 (chan-major, over dead exp_W2/S1)
    conv_k<<<dim3(32, 8, 8), 256, 0, stream>>>(XS, conv_W, XC2, XCT2);
    G3(0, 2, 32, 1, 4096, 144, 2048, XC2, 4096, 2048, LL0, LL0,
       xprojW2, 4096, 2048, LL0, LL0, dtBC, 144, 0, LL0, LL0,
       nullptr, nullptr, 0, 1.f, 1);
    dt_k<<<256, 256, 0, stream>>>(dtBC, dt_bias, DT);
    cuma_k<<<dim3(16, 8), 64, 0, stream>>>(DT, A_log, CUMA);
    gemm_f32_k<<<dim3(4, 4, 8), 256, 0, stream>>>(
        512, 512, 64, dtBC + 80, 144, (long long)512 * 144,
        dtBC + 16, 144, (long long)512 * 144, G, 512, (long long)512 * 512);
    ssd_mfma_k<<<dim3(4, 16, 8), 256, 0, stream>>>(G, CUMA, DT, XCT2, XC2, Z, Dv, YS2);

    // ---- weight prep (phase B: S3/S4 now dead) ----
    pairify(stream, outp_W, outp_W2, 11, 1024LL * 2048);
    pairify(stream, aWq, aWq2, 10, 1024LL * 1024);
    pairify(stream, aWk, aWk2, 10, 1024LL * 1024);
    pairify(stream, aWv, aWv2, 10, 1024LL * 1024);
    pairify(stream, aWo, aWo2, 10, 1024LL * 1024);
    pairify(stream, bWk, bWk2, 10, 1024LL * 1024);
    pairify(stream, bWv, bWv2, 10, 1024LL * 1024);

    G3(0, 8, 32, 1, 4096, 1024, 2048, YS2, 4096, 2048, LL0, LL0,
       outp_W2, 4096, 2048, LL0, LL0, Y1, 1024, 0, LL0, LL0,
       outp_b, T, 1024, 1.f, 1);

    // ---- encoder attention (all MFMA) ----
    layernorm_pair_k<<<4096, 256, 0, stream>>>(Y1, LNY2, n1_w, n1_b, 1024, 4096, LL0);
    G3(1, 8, 32, 1, 4096, 1024, 1024, LNY2, 2048, 1024, LL0, LL0,
       aWq2, 2048, 1024, LL0, LL0, QA2, 2048, 1024, LL0, LL0,
       nullptr, nullptr, 0, 1.f, 1);
    G3(1, 8, 32, 1, 4096, 1024, 1024, LNY2, 2048, 1024, LL0, LL0,
       aWk2, 2048, 1024, LL0, LL0, KA2, 2048, 1024, LL0, LL0,
       nullptr, nullptr, 0, 1.f, 1);
    G3(2, 8, 32, 1, 4096, 1024, 1024, LNY2, 2048, 1024, LL0, LL0,
       aWv2, 2048, 1024, LL0, LL0, VT2, 1024, 512, (long long)1024 * 1024, LL0,
       nullptr, nullptr, 0, 1.f, 1);
    G3(0, 4, 4, 32, 512, 512, 256,
       QA2, 2048, 1024, (long long)512 * 2048, 256,
       KA2, 2048, 1024, (long long)512 * 2048, 256,
       SA, 512, 0, (long long)4 * 512 * 512, (long long)512 * 512,
       nullptr, nullptr, 0, 1.f / 16.f, 4);
    softmax_pair_k<<<16384, 256, 0, stream>>>(SA, P2);
    G3(1, 2, 4, 32, 512, 256, 512,
       P2, 1024, 512, (long long)4 * 512 * 1024, (long long)512 * 1024,
       VT2, 1024, 512, (long long)1024 * 1024, (long long)256 * 1024,
       OA2, 2048, 1024, (long long)512 * 2048, 256,
       nullptr, nullptr, 0, 1.f, 4);
    G3(1, 8, 32, 1, 4096, 1024, 1024, OA2, 2048, 1024, LL0, LL0,
       aWo2, 2048, 1024, LL0, LL0, Y22, 2048, 1024, LL0, LL0,
       aWo_b, Y1, 1024, 1.f, 1);

    // ---- quantize ----
    G3(0, 1, 32, 1, 4096, 64, 1024, Y22, 2048, 1024, LL0, LL0,
       hW2, 2048, 1024, LL0, LL0, G1, 64, 0, LL0, LL0,
       h_b, nullptr, 0, 1.f, 1);
    hc_quant_k<<<4096, 64, 0, stream>>>(G1, h_lnw, h_lnb, HCQ2);

    // ---- decoder (collapsed masked rows) ----
    G3(0, 8, 32, 1, 4096, 1024, 64, HCQ2, 128, 64, LL0, LL0,
       e2dW2, 128, 64, LL0, LL0, DXV, 1024, 0, LL0, LL0,
       nullptr, nullptr, 0, 1.f, 1);
    dxm_k<<<4, 256, 0, stream>>>(mtok, e2d_W, dxm);
    layernorm_k<<<1, 256, 0, stream>>>(dxm, lnm, dn_w, dn_b, 1024, 1, LL0);
    layernorm_pair_k<<<4096, 256, 0, stream>>>(DXV, LNDXV2, dn_w, dn_b, 1024, 4096, LL0);
    projm_k<<<12, 256, 0, stream>>>(lnm, bWq, bWk, bWv, qm, km, vm);
    G1P(0, 8, 32, 1, 4096, 1024, 1024, LNDXV2, 2048, 1024, LL0, LL0,
        bWk2, 2048, 1024, LL0, LL0, Kv, 1024, 0, LL0, LL0,
        nullptr, nullptr, 0, 1.f, 1);
    G1P(0, 8, 32, 1, 4096, 1024, 1024, LNDXV2, 2048, 1024, LL0, LL0,
        bWv2, 2048, 1024, LL0, LL0, Vv, 1024, 0, LL0, LL0,
        nullptr, nullptr, 0, 1.f, 1);
    dec_attn_k<<<dim3(4, 8), 256, 0, stream>>>(Kv, Vv, qm, km, vm, OBm);
    ydm_k<<<32, 256, 0, stream>>>(OBm, bWo, bWo_b, dxm, ydm);
    outm_k<<<64, 256, 0, stream>>>(ydm, dout_W, dout_b, outm);
    bcast_k<<<8192, 256, 0, stream>>>(outm, out);
    #undef G3
    #undef G1P
}

// Round 7
// 1388.492 us; speedup vs baseline: 1.4715x; 1.1215x over previous
//
#include <hip/hip_runtime.h>

// ---------------------------------------------------------------------------
// B=8, N=1024, CIN=2048, HID=1024, HC=64, LV=512, NH_SSD=16, HD=128, DS=64.
// Encoder rows = 4096. Decoder collapsed to 1 row/batch. All large GEMMs:
// split-bf16 MFMA (x3 passes = f32-grade pre-quantizer; x1 post-quantizer),
// staged via __builtin_amdgcn_global_load_lds width=16 (DIRECT path,
// unpadded LDS rows -> lane-contiguous dest, conflict-free b128 reads).
// SSD intra-chunk = fused MFMA kernel; D-skip folded into W diagonal.
// ---------------------------------------------------------------------------

typedef short bf16x8 __attribute__((ext_vector_type(8)));
typedef float f32x4 __attribute__((ext_vector_type(4)));

__device__ __forceinline__ unsigned short bf16_rne(float f) {
    unsigned u = __float_as_uint(f);
    unsigned r = u + 0x7FFFu + ((u >> 16) & 1u);
    return (unsigned short)(r >> 16);
}
__device__ __forceinline__ float bf16_tof(unsigned short h) {
    return __uint_as_float(((unsigned)h) << 16);
}
__device__ __forceinline__ void store_pair(unsigned short* dst, long long row,
                                           int width, int c, float v) {
    unsigned short hi = bf16_rne(v);
    unsigned short lo = bf16_rne(v - bf16_tof(hi));
    long long base = row * (2LL * width);
    dst[base + c] = hi;
    dst[base + width + c] = lo;
}
// Async global->LDS, 16B per lane. LDS dest = wave-uniform base + lane*16.
__device__ __forceinline__ void async_ld16(const unsigned short* g, unsigned short* l) {
    __builtin_amdgcn_global_load_lds(
        (const __attribute__((address_space(1))) unsigned int*)g,
        (__attribute__((address_space(3))) unsigned int*)l, 16, 0, 0);
}

// ---------------------------------------------------------------------------
// Reduction helpers (blockDim 256)
// ---------------------------------------------------------------------------
__device__ __forceinline__ float block_sum256(float v) {
    #pragma unroll
    for (int o = 32; o > 0; o >>= 1) v += __shfl_xor(v, o, 64);
    __shared__ float sm[4];
    int w = threadIdx.x >> 6;
    __syncthreads();
    if ((threadIdx.x & 63) == 0) sm[w] = v;
    __syncthreads();
    return sm[0] + sm[1] + sm[2] + sm[3];
}
__device__ __forceinline__ float block_max256(float v) {
    #pragma unroll
    for (int o = 32; o > 0; o >>= 1) v = fmaxf(v, __shfl_xor(v, o, 64));
    __shared__ float smx[4];
    int w = threadIdx.x >> 6;
    __syncthreads();
    if ((threadIdx.x & 63) == 0) smx[w] = v;
    __syncthreads();
    return fmaxf(fmaxf(smx[0], smx[1]), fmaxf(smx[2], smx[3]));
}

// ---------------------------------------------------------------------------
// Split-bf16 MFMA GEMM. C[m,n] = alpha * sum_k A[m,k]*B[n,k] (+bias)(+res)
// NPASS=3: hh+lh+hl (f32-grade). NPASS=1: hh only.
// OUT=0: f32 C. OUT=1: split-pair C. OUT=2: transposed split-pair per
// 512-row batch. DIRECT=true: global_load_lds staging (requires N full
// through the tile grid); false: guarded reg staging (ragged N ok).
// ---------------------------------------------------------------------------
template<int NPASS, int OUT, bool DIRECT>
__global__ __launch_bounds__(256, 2) void gemm_bf16_k(
    int M, int N, int K,
    const unsigned short* __restrict__ A2, int lda2, int aLo, long long sAb, long long sAh,
    const unsigned short* __restrict__ B2, int ldb2, int bLo, long long sBb, long long sBh,
    void* __restrict__ Cv, int ldc, int cLo, long long sCb, long long sCh,
    const float* __restrict__ bias, const float* __restrict__ res, int ldr,
    float alpha, int nh)
{
    constexpr int ST = DIRECT ? 32 : 40;
    __shared__ unsigned short Ah[128 * ST];
    __shared__ unsigned short Bh[128 * ST];
    __shared__ unsigned short Al[128 * ST];
    __shared__ unsigned short Bl[128 * ST];

    const int z  = blockIdx.z;
    const int bb = z / nh, hh = z - bb * nh;
    A2 += bb * sAb + hh * sAh;
    B2 += bb * sBb + hh * sBh;

    const int t    = threadIdx.x;
    const int m0   = blockIdx.y * 128;
    const int n0   = blockIdx.x * 128;
    const int lane = t & 63, wave = t >> 6;
    const int wm   = (wave >> 1) * 64, wn = (wave & 1) * 64;
    const int lr   = lane & 15, quad = lane >> 4;

    f32x4 acc[4][4];
    #pragma unroll
    for (int i = 0; i < 4; ++i)
        #pragma unroll
        for (int j = 0; j < 4; ++j) acc[i][j] = (f32x4){0.f, 0.f, 0.f, 0.f};

    // staging coords
    const int srow = t >> 2;          // ragged path: row 0..63 (+64)
    const int scol = (t & 3) * 8;
    const int drow = lane >> 2;       // DIRECT: row within 16-row chunk
    const int dcol = (lane & 3) * 8;

    for (int k0 = 0; k0 < K; k0 += 32) {
        __syncthreads();
        if (DIRECT) {
            #pragma unroll
            for (int j = 0; j < 2; ++j) {
                int rr = wave * 32 + j * 16;          // chunk base row
                int gr = rr + drow;
                const unsigned short* gA = A2 + (long long)(m0 + gr) * lda2 + k0 + dcol;
                async_ld16(gA, &Ah[rr * 32]);
                if (NPASS == 3) async_ld16(gA + aLo, &Al[rr * 32]);
                const unsigned short* gB = B2 + (long long)(n0 + gr) * ldb2 + k0 + dcol;
                async_ld16(gB, &Bh[rr * 32]);
                if (NPASS == 3) async_ld16(gB + bLo, &Bl[rr * 32]);
            }
        } else {
            #pragma unroll
            for (int half = 0; half < 2; ++half) {
                int r = srow + half * 64;
                const unsigned short* pA = A2 + (long long)(m0 + r) * lda2 + k0 + scol;
                *(uint4*)&Ah[r * ST + scol] = *(const uint4*)pA;
                if (NPASS == 3)
                    *(uint4*)&Al[r * ST + scol] = *(const uint4*)(pA + aLo);
                int rb = n0 + r;
                uint4 vh = {0u, 0u, 0u, 0u}, vl = {0u, 0u, 0u, 0u};
                if (rb < N) {
                    const unsigned short* pB = B2 + (long long)rb * ldb2 + k0 + scol;
                    vh = *(const uint4*)pB;
                    if (NPASS == 3) vl = *(const uint4*)(pB + bLo);
                }
                *(uint4*)&Bh[r * ST + scol] = vh;
                if (NPASS == 3) *(uint4*)&Bl[r * ST + scol] = vl;
            }
        }
        __syncthreads();

        bf16x8 ah[4], bh[4], al[4], bl[4];
        #pragma unroll
        for (int i = 0; i < 4; ++i) {
            int ra = (wm + i * 16 + lr) * ST + quad * 8;
            int rb = (wn + i * 16 + lr) * ST + quad * 8;
            ah[i] = *(const bf16x8*)&Ah[ra];
            bh[i] = *(const bf16x8*)&Bh[rb];
            if (NPASS == 3) {
                al[i] = *(const bf16x8*)&Al[ra];
                bl[i] = *(const bf16x8*)&Bl[rb];
            }
        }
        #pragma unroll
        for (int mi = 0; mi < 4; ++mi)
            #pragma unroll
            for (int ni = 0; ni < 4; ++ni) {
                acc[mi][ni] = __builtin_amdgcn_mfma_f32_16x16x32_bf16(
                    ah[mi], bh[ni], acc[mi][ni], 0, 0, 0);
                if (NPASS == 3) {
                    acc[mi][ni] = __builtin_amdgcn_mfma_f32_16x16x32_bf16(
                        al[mi], bh[ni], acc[mi][ni], 0, 0, 0);
                    acc[mi][ni] = __builtin_amdgcn_mfma_f32_16x16x32_bf16(
                        ah[mi], bl[ni], acc[mi][ni], 0, 0, 0);
                }
            }
    }

    // D layout: col = lane&15, row = quad*4 + r
    if (OUT == 0) {
        float* C = (float*)Cv + bb * sCb + hh * sCh;
        #pragma unroll
        for (int mi = 0; mi < 4; ++mi)
            #pragma unroll
            for (int ni = 0; ni < 4; ++ni) {
                int col = n0 + wn + ni * 16 + lr;
                if (col >= N) continue;
                float bv = bias ? bias[col] : 0.f;
                #pragma unroll
                for (int r = 0; r < 4; ++r) {
                    int row = m0 + wm + mi * 16 + quad * 4 + r;
                    float v = alpha * acc[mi][ni][r] + bv;
                    if (res) v += res[(long long)row * ldr + col];
                    C[(long long)row * ldc + col] = v;
                }
            }
    } else if (OUT == 1) {
        unsigned short* C = (unsigned short*)Cv + bb * sCb + hh * sCh;
        #pragma unroll
        for (int mi = 0; mi < 4; ++mi)
            #pragma unroll
            for (int ni = 0; ni < 4; ++ni) {
                int col = n0 + wn + ni * 16 + lr;
                if (col >= N) continue;
                float bv = bias ? bias[col] : 0.f;
                #pragma unroll
                for (int r = 0; r < 4; ++r) {
                    int row = m0 + wm + mi * 16 + quad * 4 + r;
                    float v = alpha * acc[mi][ni][r] + bv;
                    if (res) v += res[(long long)row * ldr + col];
                    unsigned short hi = bf16_rne(v);
                    unsigned short lo = bf16_rne(v - bf16_tof(hi));
                    long long p = (long long)row * ldc + col;
                    C[p] = hi;
                    C[p + cLo] = lo;
                }
            }
    } else {  // OUT == 2: transposed pairs per 512-row batch
        unsigned short* C = (unsigned short*)Cv;
        #pragma unroll
        for (int mi = 0; mi < 4; ++mi)
            #pragma unroll
            for (int ni = 0; ni < 4; ++ni) {
                int col = n0 + wn + ni * 16 + lr;
                if (col >= N) continue;
                int row0 = m0 + wm + mi * 16 + quad * 4;
                int b = row0 >> 9, seq0 = row0 & 511;
                ushort4 h4, l4;
                unsigned short* hp = (unsigned short*)&h4;
                unsigned short* lp = (unsigned short*)&l4;
                #pragma unroll
                for (int r = 0; r < 4; ++r) {
                    float v = acc[mi][ni][r];
                    unsigned short hi = bf16_rne(v);
                    hp[r] = hi;
                    lp[r] = bf16_rne(v - bf16_tof(hi));
                }
                long long p = b * sCb + (long long)col * ldc + seq0;
                *(ushort4*)&C[p] = h4;
                *(ushort4*)&C[p + cLo] = l4;
            }
    }
}

// ---------------------------------------------------------------------------
// Fused SSD intra-chunk MFMA kernel, v2.
// Per (b,h): Y[l,p] = sum_{s<=l} W[l,s]*XC[s,p];
// W = G*exp(cAl-cAs)*dt[s], with D-skip folded in: W[l,l] += D[h].
// Block = 128 l x 64 p (p-split for 2x grid). W split-pairs in LDS
// (unpadded, b128 vector writes); X fragments from chan-major XCT2.
// Epilogue: y = acc * silu(Z) -> seq-major pairs YS2.
// grid (8 = 2p x 4mt, 16 h, 8 b), block 256 (4 waves x 32l x 64p).
// ---------------------------------------------------------------------------
__global__ __launch_bounds__(256, 2) void ssd_mfma_k(
    const float* __restrict__ G, const float* __restrict__ CUMA,
    const float* __restrict__ DT, const unsigned short* __restrict__ XCT2,
    const float* __restrict__ Z, const float* __restrict__ Dv,
    unsigned short* __restrict__ YS2)
{
    __shared__ unsigned short Wh[128 * 32];
    __shared__ unsigned short Wl[128 * 32];
    __shared__ float Cs[512];
    __shared__ float Ds[512];
    const int mt = blockIdx.x >> 1, ph = blockIdx.x & 1;
    const int h = blockIdx.y, b = blockIdx.z;
    const int t = threadIdx.x;
    const int lane = t & 63, wave = t >> 6;
    const int wm = wave * 32;
    const int lr = lane & 15, quad = lane >> 4;
    const int m0 = mt * 128;
    const int kend = m0 + 128;

    const float* cbase = CUMA + (b * 16 + h) * 512;
    const float* dtb = DT + (long long)b * 512 * 16 + h;
    for (int s = t; s < 512; s += 256) {
        Cs[s] = cbase[s];
        Ds[s] = dtb[(long long)s * 16];
    }
    __syncthreads();

    const int wlt = t >> 1;             // l local 0..127
    const int s0 = (t & 1) * 16;        // s offset within 32-tile
    const int lglob = m0 + wlt;
    const float cAl = Cs[lglob];
    const float Dh = Dv[h];
    const float* grow = G + ((long long)(b * 512 + lglob)) * 512;

    f32x4 acc[2][4];
    #pragma unroll
    for (int i = 0; i < 2; ++i)
        #pragma unroll
        for (int j = 0; j < 4; ++j) acc[i][j] = (f32x4){0.f, 0.f, 0.f, 0.f};

    const unsigned short* XB = XCT2 + (long long)b * 2097152
                             + (long long)(h * 128 + ph * 64) * 1024;

    for (int k0 = 0; k0 < kend; k0 += 32) {
        __syncthreads();
        unsigned short hv[16], lv[16];
        #pragma unroll
        for (int q = 0; q < 4; ++q) {
            float4 g4 = *(const float4*)(grow + k0 + s0 + q * 4);
            float gg[4] = {g4.x, g4.y, g4.z, g4.w};
            #pragma unroll
            for (int e = 0; e < 4; ++e) {
                int sg = k0 + s0 + q * 4 + e;
                float w = 0.f;
                if (sg <= lglob)
                    w = gg[e] * __expf(cAl - Cs[sg]) * Ds[sg];
                if (sg == lglob) w += Dh;
                unsigned short hi = bf16_rne(w);
                hv[q * 4 + e] = hi;
                lv[q * 4 + e] = bf16_rne(w - bf16_tof(hi));
            }
        }
        *(uint4*)&Wh[wlt * 32 + s0]     = *(uint4*)&hv[0];
        *(uint4*)&Wh[wlt * 32 + s0 + 8] = *(uint4*)&hv[8];
        *(uint4*)&Wl[wlt * 32 + s0]     = *(uint4*)&lv[0];
        *(uint4*)&Wl[wlt * 32 + s0 + 8] = *(uint4*)&lv[8];
        __syncthreads();

        bf16x8 ah[2], al[2];
        #pragma unroll
        for (int mi = 0; mi < 2; ++mi) {
            int ra = (wm + mi * 16 + lr) * 32 + quad * 8;
            ah[mi] = *(const bf16x8*)&Wh[ra];
            al[mi] = *(const bf16x8*)&Wl[ra];
        }
        #pragma unroll
        for (int ni = 0; ni < 4; ++ni) {
            const unsigned short* pB = XB + (long long)(ni * 16 + lr) * 1024 + k0 + quad * 8;
            bf16x8 bh = *(const bf16x8*)pB;
            bf16x8 bl = *(const bf16x8*)(pB + 512);
            #pragma unroll
            for (int mi = 0; mi < 2; ++mi) {
                acc[mi][ni] = __builtin_amdgcn_mfma_f32_16x16x32_bf16(
                    ah[mi], bh, acc[mi][ni], 0, 0, 0);
                acc[mi][ni] = __builtin_amdgcn_mfma_f32_16x16x32_bf16(
                    al[mi], bh, acc[mi][ni], 0, 0, 0);
                acc[mi][ni] = __builtin_amdgcn_mfma_f32_16x16x32_bf16(
                    ah[mi], bl, acc[mi][ni], 0, 0, 0);
            }
        }
    }

    #pragma unroll
    for (int mi = 0; mi < 2; ++mi)
        #pragma unroll
        for (int ni = 0; ni < 4; ++ni) {
            int chan = h * 128 + ph * 64 + ni * 16 + lr;
            int row0 = m0 + wm + mi * 16 + quad * 4;
            #pragma unroll
            for (int r = 0; r < 4; ++r) {
                long long row = (long long)(b * 512 + row0 + r);
                float zz = Z[row * 2048 + chan];
                float y = acc[mi][ni][r] * (zz / (1.f + expf(-zz)));
                store_pair(YS2, row, 2048, chan, y);
            }
        }
}

// ---------------------------------------------------------------------------
// Tiled f32 GEMM (only for the small batched G = Cm @ Bm^T)
// ---------------------------------------------------------------------------
__global__ __launch_bounds__(256) void gemm_f32_k(
    int M, int N, int K,
    const float* __restrict__ A, int lda, long long sAb,
    const float* __restrict__ B, int ldb, long long sBb,
    float* __restrict__ C, int ldc, long long sCb)
{
    __shared__ float As[32][132];
    __shared__ float Bs[32][132];
    const int z = blockIdx.z;
    A += z * sAb; B += z * sBb; C += z * sCb;
    const int n0 = blockIdx.x * 128;
    const int m0 = blockIdx.y * 128;
    const int t  = threadIdx.x;
    const int tx = t & 15, ty = t >> 4;

    float acc[4][16];
    #pragma unroll
    for (int a = 0; a < 4; ++a)
        #pragma unroll
        for (int q = 0; q < 16; ++q) acc[a][q] = 0.f;

    const int ka = (t & 7) << 2;
    const int ra = t >> 3;

    for (int k0 = 0; k0 < K; k0 += 32) {
        __syncthreads();
        #pragma unroll
        for (int i = 0; i < 4; ++i) {
            int row = m0 + ra + i * 32;
            float4 v = *(const float4*)(A + (long long)row * lda + (k0 + ka));
            As[ka + 0][ra + i * 32] = v.x;
            As[ka + 1][ra + i * 32] = v.y;
            As[ka + 2][ra + i * 32] = v.z;
            As[ka + 3][ra + i * 32] = v.w;
            int rowb = n0 + ra + i * 32;
            float4 w = *(const float4*)(B + (long long)rowb * ldb + (k0 + ka));
            Bs[ka + 0][ra + i * 32] = w.x;
            Bs[ka + 1][ra + i * 32] = w.y;
            Bs[ka + 2][ra + i * 32] = w.z;
            Bs[ka + 3][ra + i * 32] = w.w;
        }
        __syncthreads();
        #pragma unroll
        for (int kk = 0; kk < 32; ++kk) {
            float a[8], bm[8];
            *(float4*)&a[0]  = *(const float4*)&As[kk][ty * 4];
            *(float4*)&a[4]  = *(const float4*)&As[kk][64 + ty * 4];
            *(float4*)&bm[0] = *(const float4*)&Bs[kk][tx * 4];
            *(float4*)&bm[4] = *(const float4*)&Bs[kk][64 + tx * 4];
            #pragma unroll
            for (int ri = 0; ri < 2; ++ri)
                #pragma unroll
                for (int ci = 0; ci < 2; ++ci)
                    #pragma unroll
                    for (int i = 0; i < 4; ++i)
                        #pragma unroll
                        for (int j = 0; j < 4; ++j)
                            acc[ri * 2 + ci][i * 4 + j] =
                                fmaf(a[ri * 4 + i], bm[ci * 4 + j], acc[ri * 2 + ci][i * 4 + j]);
        }
    }
    #pragma unroll
    for (int ri = 0; ri < 2; ++ri)
        #pragma unroll
        for (int ci = 0; ci < 2; ++ci) {
            int colb = n0 + ci * 64 + tx * 4;
            #pragma unroll
            for (int i = 0; i < 4; ++i) {
                int row = m0 + ri * 64 + ty * 4 + i;
                *(float4*)(C + (long long)row * ldc + colb) =
                    *(float4*)&acc[ri * 2 + ci][i * 4];
            }
        }
}

// ---------------------------------------------------------------------------
// Elementwise / norm kernels
// ---------------------------------------------------------------------------
__global__ __launch_bounds__(256) void pairify_k(
    const float* __restrict__ src, unsigned short* __restrict__ dst,
    int k_log2, long long n)
{
    long long idx = (long long)blockIdx.x * 256 + threadIdx.x;
    if (idx >= n) return;
    long long r = idx >> k_log2;
    int c = (int)(idx & ((1 << k_log2) - 1));
    store_pair(dst, r, 1 << k_log2, c, src[idx]);
}

__global__ __launch_bounds__(256) void layernorm_k(
    const float* __restrict__ in, float* __restrict__ out,
    const float* __restrict__ w, const float* __restrict__ b,
    int width, int rows_per_b, long long in_bstride)
{
    long long r = blockIdx.x;
    const float* x = in + (r / rows_per_b) * in_bstride + (r % rows_per_b) * (long long)width;
    int t = threadIdx.x;
    float s = 0.f;
    for (int c = t; c < width; c += 256) s += x[c];
    s = block_sum256(s);
    float m = s / (float)width;
    float vs = 0.f;
    for (int c = t; c < width; c += 256) { float d = x[c] - m; vs += d * d; }
    vs = block_sum256(vs);
    float rs = 1.f / sqrtf(vs / (float)width + 1e-5f);
    float* o = out + r * (long long)width;
    for (int c = t; c < width; c += 256) o[c] = (x[c] - m) * rs * w[c] + b[c];
}

__global__ __launch_bounds__(256) void layernorm_pair_k(
    const float* __restrict__ in, unsigned short* __restrict__ out2,
    const float* __restrict__ w, const float* __restrict__ b,
    int width, int rows_per_b, long long in_bstride)
{
    long long r = blockIdx.x;
    const float* x = in + (r / rows_per_b) * in_bstride + (r % rows_per_b) * (long long)width;
    int t = threadIdx.x;
    float s = 0.f;
    for (int c = t; c < width; c += 256) s += x[c];
    s = block_sum256(s);
    float m = s / (float)width;
    float vs = 0.f;
    for (int c = t; c < width; c += 256) { float d = x[c] - m; vs += d * d; }
    vs = block_sum256(vs);
    float rs = 1.f / sqrtf(vs / (float)width + 1e-5f);
    for (int c = t; c < width; c += 256)
        store_pair(out2, r, width, c, (x[c] - m) * rs * w[c] + b[c]);
}

__global__ __launch_bounds__(256) void rmsnorm_pair_k(
    const float* __restrict__ in, unsigned short* __restrict__ out2,
    const float* __restrict__ w, int width)
{
    long long r = blockIdx.x;
    const float* x = in + r * (long long)width;
    int t = threadIdx.x;
    float s = 0.f;
    for (int c = t; c < width; c += 256) { float v = x[c]; s += v * v; }
    s = block_sum256(s);
    float rs = 1.f / sqrtf(s / (float)width + 1e-5f);
    for (int c = t; c < width; c += 256)
        store_pair(out2, r, width, c, x[c] * rs * w[c]);
}

// Softmax over 512-wide rows, f32 in -> split-pair out IN-PLACE (same bytes).
__global__ __launch_bounds__(256) void softmax_pair_k(float* __restrict__ S,
                                                      unsigned short* __restrict__ P2)
{
    long long r = blockIdx.x;
    float* x = S + r * 512;
    unsigned short* p = P2 + r * 1024;
    int t = threadIdx.x;
    float v0 = x[t], v1 = x[t + 256];
    float mx = block_max256(fmaxf(v0, v1));
    v0 = expf(v0 - mx); v1 = expf(v1 - mx);
    float sum = block_sum256(v0 + v1);
    float inv = 1.f / sum;
    v0 *= inv; v1 *= inv;
    __syncthreads();
    unsigned short h0 = bf16_rne(v0);
    p[t] = h0;       p[512 + t] = bf16_rne(v0 - bf16_tof(h0));
    unsigned short h1 = bf16_rne(v1);
    p[t + 256] = h1; p[512 + t + 256] = bf16_rne(v1 - bf16_tof(h1));
}

// Causal grouped conv with LDS-tile transpose: writes seq-major pairs XC2
// AND chan-major pairs XCT2, both coalesced.
__global__ __launch_bounds__(256) void conv_k(
    const float* __restrict__ XS, const float* __restrict__ W,
    unsigned short* __restrict__ XC2, unsigned short* __restrict__ XCT2)
{
    __shared__ float tile[64][65];
    const int o0  = blockIdx.x * 64;
    const int tt0 = blockIdx.y * 64;
    const int b   = blockIdx.z;
    const int t   = threadIdx.x;

    const int o  = o0 + (t & 63);
    const int g2 = (o >> 1) << 1;
    const float* Wo = W + o * 8;
    float w0 = Wo[0], w1 = Wo[1], w2 = Wo[2], w3 = Wo[3];
    float w4 = Wo[4], w5 = Wo[5], w6 = Wo[6], w7 = Wo[7];
    #pragma unroll
    for (int i = 0; i < 16; ++i) {
        int sl = (t >> 6) + 4 * i;
        int tt = tt0 + sl;
        const float* xb = XS + ((long long)(b * 512 + tt)) * 2048 + g2;
        float acc = w3 * xb[0] + w7 * xb[1];
        if (tt >= 1) acc += w2 * xb[-2048] + w6 * xb[-2047];
        if (tt >= 2) acc += w1 * xb[-4096] + w5 * xb[-4095];
        if (tt >= 3) acc += w0 * xb[-6144] + w4 * xb[-6143];
        tile[sl][t & 63] = acc;
    }
    __syncthreads();
    #pragma unroll
    for (int i = 0; i < 16; ++i) {
        int idx = t + 256 * i;
        int sl = idx >> 6, ol = idx & 63;
        float v = tile[sl][ol];
        unsigned short hi = bf16_rne(v);
        unsigned short lo = bf16_rne(v - bf16_tof(hi));
        long long row = (long long)(b * 512 + tt0 + sl);
        XC2[row * 4096 + o0 + ol] = hi;
        XC2[row * 4096 + 2048 + o0 + ol] = lo;
    }
    #pragma unroll
    for (int i = 0; i < 16; ++i) {
        int idx = t + 256 * i;
        int cl = idx >> 6, s = idx & 63;
        float v = tile[s][cl];
        unsigned short hi = bf16_rne(v);
        unsigned short lo = bf16_rne(v - bf16_tof(hi));
        long long tb = (long long)b * 2097152 + (long long)(o0 + cl) * 1024 + tt0 + s;
        XCT2[tb] = hi;
        XCT2[tb + 512] = lo;
    }
}

__global__ __launch_bounds__(256) void dt_k(
    const float* __restrict__ dtBC, const float* __restrict__ dt_bias, float* __restrict__ DT)
{
    int idx = blockIdx.x * 256 + threadIdx.x;
    int r = idx >> 4, h = idx & 15;
    float xv = dtBC[r * 144 + h] + dt_bias[h];
    DT[idx] = (xv > 20.f) ? xv : log1pf(expf(xv));
}

__global__ __launch_bounds__(64) void cuma_k(
    const float* __restrict__ DT, const float* __restrict__ A_log, float* __restrict__ CUMA)
{
    int h = blockIdx.x, b = blockIdx.y;
    int ln = threadIdx.x;
    float Ah = -expf(A_log[h]);
    float v[8];
    float run = 0.f;
    #pragma unroll
    for (int i = 0; i < 8; ++i) {
        run += Ah * DT[((b * 512) + (ln * 8 + i)) * 16 + h];
        v[i] = run;
    }
    float tot = run;
    float sc = tot;
    #pragma unroll
    for (int o = 1; o <= 32; o <<= 1) {
        float u = __shfl_up(sc, o, 64);
        if (ln >= o) sc += u;
    }
    float excl = sc - tot;
    #pragma unroll
    for (int i = 0; i < 8; ++i)
        CUMA[(b * 16 + h) * 512 + ln * 8 + i] = excl + v[i];
}

// hc = LayerNorm64(G1) -> {-1,+1} as split pairs (lo = 0)
__global__ __launch_bounds__(64) void hc_quant_k(
    const float* __restrict__ G1, const float* __restrict__ w,
    const float* __restrict__ b, unsigned short* __restrict__ HCQ2)
{
    int r = blockIdx.x, ln = threadIdx.x;
    float v = G1[r * 64 + ln];
    float s = v;
    #pragma unroll
    for (int o = 32; o > 0; o >>= 1) s += __shfl_xor(s, o, 64);
    float m = s * (1.f / 64.f);
    float d = v - m;
    float vs = d * d;
    #pragma unroll
    for (int o = 32; o > 0; o >>= 1) vs += __shfl_xor(vs, o, 64);
    vs *= (1.f / 64.f);
    float hc = d * (1.f / sqrtf(vs + 1e-5f)) * w[ln] + b[ln];
    HCQ2[r * 128 + ln] = (hc > 0.f) ? 0x3F80 : 0xBF80;
    HCQ2[r * 128 + 64 + ln] = 0;
}

__global__ __launch_bounds__(256) void dxm_k(
    const float* __restrict__ mtok, const float* __restrict__ e2d, float* __restrict__ dxm)
{
    int c = blockIdx.x * 256 + threadIdx.x;
    float acc = 0.f;
    #pragma unroll
    for (int j = 0; j < 64; ++j) acc = fmaf(mtok[j], e2d[c * 64 + j], acc);
    dxm[c] = acc;
}

__global__ __launch_bounds__(256) void projm_k(
    const float* __restrict__ lnm,
    const float* __restrict__ bWq, const float* __restrict__ bWk, const float* __restrict__ bWv,
    float* __restrict__ qm, float* __restrict__ km, float* __restrict__ vm)
{
    int idx = blockIdx.x * 256 + threadIdx.x;
    int sel = idx >> 10, c = idx & 1023;
    const float* W = (sel == 0) ? bWq : (sel == 1) ? bWk : bWv;
    float* O = (sel == 0) ? qm : (sel == 1) ? km : vm;
    const float* wr = W + (long long)c * 1024;
    float acc = 0.f;
    for (int j = 0; j < 1024; j += 4) {
        float4 a = *(const float4*)(lnm + j);
        float4 w4 = *(const float4*)(wr + j);
        acc = fmaf(a.x, w4.x, fmaf(a.y, w4.y, fmaf(a.z, w4.z, fmaf(a.w, w4.w, acc))));
    }
    O[c] = acc;
}

// Collapsed decoder attention: 1 query/(b,h); keys = 512 visible + mask key x512.
__global__ __launch_bounds__(256) void dec_attn_k(
    const float* __restrict__ Kv, const float* __restrict__ Vv,
    const float* __restrict__ qm, const float* __restrict__ km,
    const float* __restrict__ vm, float* __restrict__ OBm)
{
    int h = blockIdx.x, b = blockIdx.y;
    int t = threadIdx.x;
    __shared__ __align__(16) float qs[256];
    __shared__ __align__(16) float ps[512];
    qs[t] = qm[h * 256 + t];
    __syncthreads();
    float s[2];
    #pragma unroll
    for (int i = 0; i < 2; ++i) {
        int r = t + i * 256;
        const float* kr = Kv + ((long long)(b * 512 + r)) * 1024 + h * 256;
        float acc = 0.f;
        for (int c = 0; c < 256; c += 4) {
            float4 k4 = *(const float4*)(kr + c);
            float4 q4 = *(const float4*)(qs + c);
            acc = fmaf(k4.x, q4.x, fmaf(k4.y, q4.y, fmaf(k4.z, q4.z, fmaf(k4.w, q4.w, acc))));
        }
        s[i] = acc * (1.f / 16.f);
    }
    float accm = 0.f;
    for (int c = 0; c < 256; c += 4) {
        float4 k4 = *(const float4*)(km + h * 256 + c);
        float4 q4 = *(const float4*)(qs + c);
        accm = fmaf(k4.x, q4.x, fmaf(k4.y, q4.y, fmaf(k4.z, q4.z, fmaf(k4.w, q4.w, accm))));
    }
    float smv = accm * (1.f / 16.f);
    float mx = block_max256(fmaxf(fmaxf(s[0], s[1]), smv));
    float p0 = expf(s[0] - mx), p1 = expf(s[1] - mx);
    ps[t] = p0; ps[t + 256] = p1;
    float pm = expf(smv - mx) * 512.f;
    float sum = block_sum256(p0 + p1) + pm;
    float inv = 1.f / sum;
    __syncthreads();
    float o = pm * vm[h * 256 + t];
    const float* vcol = Vv + (long long)b * 512 * 1024 + h * 256 + t;
    for (int j = 0; j < 512; ++j)
        o = fmaf(ps[j], vcol[(long long)j * 1024], o);
    OBm[b * 1024 + h * 256 + t] = o * inv;
}

__global__ __launch_bounds__(256) void ydm_k(
    const float* __restrict__ OBm, const float* __restrict__ bWo,
    const float* __restrict__ bWo_b, const float* __restrict__ dxm,
    float* __restrict__ ydm)
{
    int idx = blockIdx.x * 256 + threadIdx.x;
    int b = idx >> 10, c = idx & 1023;
    const float* ar = OBm + b * 1024;
    const float* wr = bWo + (long long)c * 1024;
    float acc = 0.f;
    for (int j = 0; j < 1024; j += 4) {
        float4 a = *(const float4*)(ar + j);
        float4 w4 = *(const float4*)(wr + j);
        acc = fmaf(a.x, w4.x, fmaf(a.y, w4.y, fmaf(a.z, w4.z, fmaf(a.w, w4.w, acc))));
    }
    ydm[idx] = acc + bWo_b[c] + dxm[c];
}

__global__ __launch_bounds__(256) void outm_k(
    const float* __restrict__ ydm, const float* __restrict__ dout_W,
    const float* __restrict__ dout_b, float* __restrict__ outm)
{
    int idx = blockIdx.x * 256 + threadIdx.x;
    int b = idx >> 11, c = idx & 2047;
    const float* ar = ydm + b * 1024;
    const float* wr = dout_W + (long long)c * 1024;
    float acc = 0.f;
    for (int j = 0; j < 1024; j += 4) {
        float4 a = *(const float4*)(ar + j);
        float4 w4 = *(const float4*)(wr + j);
        acc = fmaf(a.x, w4.x, fmaf(a.y, w4.y, fmaf(a.z, w4.z, fmaf(a.w, w4.w, acc))));
    }
    outm[idx] = acc + dout_b[c];
}

__global__ __launch_bounds__(256) void bcast_k(
    const float* __restrict__ outm, float* __restrict__ out)
{
    int idx = blockIdx.x * 256 + threadIdx.x;
    int c4 = idx & 511;
    int b = idx >> 18;
    ((float4*)out)[idx] = ((const float4*)outm)[b * 512 + c4];
}

// ---------------------------------------------------------------------------
// Host-side launcher
// ---------------------------------------------------------------------------
static inline void pairify(hipStream_t s, const float* src, unsigned short* dst,
                           int k_log2, long long n)
{
    pairify_k<<<(int)((n + 255) / 256), 256, 0, s>>>(src, dst, k_log2, n);
}

extern "C" void kernel_launch(void* const* d_in, const int* in_sizes, int n_in,
                              void* d_out, int out_size, void* d_ws, size_t ws_size,
                              hipStream_t stream)
{
    const float* x       = (const float*)d_in[0];
    const float* ln0_w   = (const float*)d_in[1];
    const float* ln0_b   = (const float*)d_in[2];
    const float* in_W    = (const float*)d_in[3];
    const float* rms_w   = (const float*)d_in[4];
    const float* exp_W   = (const float*)d_in[5];
    const float* conv_W  = (const float*)d_in[6];
    const float* xproj_W = (const float*)d_in[7];
    const float* dt_bias = (const float*)d_in[8];
    const float* A_log   = (const float*)d_in[9];
    const float* Dv      = (const float*)d_in[10];
    const float* outp_W  = (const float*)d_in[11];
    const float* outp_b  = (const float*)d_in[12];
    const float* n1_w    = (const float*)d_in[13];
    const float* n1_b    = (const float*)d_in[14];
    const float* aWq     = (const float*)d_in[15];
    const float* aWk     = (const float*)d_in[16];
    const float* aWv     = (const float*)d_in[17];
    const float* aWo     = (const float*)d_in[18];
    const float* aWo_b   = (const float*)d_in[19];
    const float* h_W     = (const float*)d_in[20];
    const float* h_b     = (const float*)d_in[21];
    const float* h_lnw   = (const float*)d_in[22];
    const float* h_lnb   = (const float*)d_in[23];
    const float* mtok    = (const float*)d_in[24];
    const float* e2d_W   = (const float*)d_in[25];
    const float* dn_w    = (const float*)d_in[26];
    const float* dn_b    = (const float*)d_in[27];
    const float* bWq     = (const float*)d_in[28];
    const float* bWk     = (const float*)d_in[29];
    const float* bWv     = (const float*)d_in[30];
    const float* bWo     = (const float*)d_in[31];
    const float* bWo_b   = (const float*)d_in[32];
    const float* dout_W  = (const float*)d_in[33];
    const float* dout_b  = (const float*)d_in[34];

    float* ws  = (float*)d_ws;
    float* out = (float*)d_out;

    float* S1 = ws;
    float* S2 = ws + 8388608;
    float* S3 = ws + 16777216;
    float* S4 = ws + 25165824;
    float* S5 = ws + 33554432;
    float* S6 = ws + 37748736;
    float* S7 = ws + 41943040;
    float* S8 = ws + 46137344;
    float* S9 = ws + 50331648;
    float* SP = ws + 54525952;

    unsigned short* XV2     = (unsigned short*)S1;
    unsigned short* exp_W2  = (unsigned short*)S1;
    unsigned short* XCT2    = (unsigned short*)S1;
    float*          SA      = S1;
    unsigned short* P2      = (unsigned short*)S1;
    float*          Kv      = S1;
    float*          Vv      = S1 + 4194304;
    unsigned short* in_W2   = (unsigned short*)S2;
    float*          XS      = S2;
    unsigned short* YS2     = (unsigned short*)S2;
    unsigned short* XC2     = (unsigned short*)S3;
    unsigned short* outp_W2 = (unsigned short*)S3;
    float*          DXV     = S3;
    unsigned short* LNDXV2  = (unsigned short*)(S3 + 4194304);
    float*          Z       = S4;
    unsigned short* aWq2    = (unsigned short*)S4;
    unsigned short* aWk2    = (unsigned short*)S4 + 2097152;
    unsigned short* aWv2    = (unsigned short*)S4 + 4194304;
    unsigned short* aWo2    = (unsigned short*)S4 + 6291456;
    unsigned short* bWk2    = (unsigned short*)S4 + 8388608;
    unsigned short* bWv2    = (unsigned short*)S4 + 10485760;
    float*          T       = S5;
    unsigned short* QA2     = (unsigned short*)S5;
    unsigned short* Y22     = (unsigned short*)S5;
    unsigned short* HR2     = (unsigned short*)S6;
    float*          Y1      = S6;
    unsigned short* LNY2    = (unsigned short*)S7;
    unsigned short* OA2     = (unsigned short*)S7;
    unsigned short* KA2     = (unsigned short*)S8;
    unsigned short* VT2     = (unsigned short*)S9;

    float* dtBC = SP;
    float* DT   = SP + 589824;
    float* CUMA = SP + 655360;
    float* G    = SP + 720896;
    unsigned short* xprojW2 = (unsigned short*)(SP + 2818048);
    unsigned short* hW2     = (unsigned short*)(SP + 3112960);
    unsigned short* e2dW2   = (unsigned short*)(SP + 3178496);
    float* G1   = SP + 720896;
    unsigned short* HCQ2 = (unsigned short*)(SP + 983040);
    float* dxm  = SP + 1245184;
    float* lnm  = SP + 1246208;
    float* qm   = SP + 1247232;
    float* km   = SP + 1248256;
    float* vm   = SP + 1249280;
    float* OBm  = SP + 1250304;
    float* ydm  = SP + 1258496;
    float* outm = SP + 1266688;

    const long long LL0 = 0;
    #define G3D(OUTM, GX, GY, GZ, ...) \
        gemm_bf16_k<3, OUTM, true><<<dim3(GX, GY, GZ), 256, 0, stream>>>(__VA_ARGS__)
    #define G3R(OUTM, GX, GY, GZ, ...) \
        gemm_bf16_k<3, OUTM, false><<<dim3(GX, GY, GZ), 256, 0, stream>>>(__VA_ARGS__)
    #define G1D(OUTM, GX, GY, GZ, ...) \
        gemm_bf16_k<1, OUTM, true><<<dim3(GX, GY, GZ), 256, 0, stream>>>(__VA_ARGS__)

    // ---- weight prep (phase A) ----
    pairify(stream, in_W,    in_W2,   11, 1024LL * 2048);
    pairify(stream, xproj_W, xprojW2, 11, 144LL * 2048);
    pairify(stream, h_W,     hW2,     10, 64LL * 1024);
    pairify(stream, e2d_W,   e2dW2,    6, 1024LL * 64);

    // ---- encoder trunk ----
    layernorm_pair_k<<<4096, 256, 0, stream>>>(x, XV2, ln0_w, ln0_b, 2048, 512,
                                               (long long)1024 * 2048);
    G3D(0, 8, 32, 1, 4096, 1024, 2048, XV2, 4096, 2048, LL0, LL0,
        in_W2, 4096, 2048, LL0, LL0, T, 1024, 0, LL0, LL0,
        nullptr, nullptr, 0, 1.f, 1);
    pairify(stream, exp_W, exp_W2, 10, 4096LL * 1024);   // S1 (XV2 dead)
    rmsnorm_pair_k<<<4096, 256, 0, stream>>>(T, HR2, rms_w, 1024);
    G3D(0, 16, 32, 1, 4096, 2048, 1024, HR2, 2048, 1024, LL0, LL0,
        exp_W2, 2048, 1024, LL0, LL0, XS, 2048, 0, LL0, LL0,
        nullptr, nullptr, 0, 1.f, 1);
    G3D(0, 16, 32, 1, 4096, 2048, 1024, HR2, 2048, 1024, LL0, LL0,
        exp_W2 + 2048LL * 2048, 2048, 1024, LL0, LL0, Z, 2048, 0, LL0, LL0,
        nullptr, nullptr, 0, 1.f, 1);
    conv_k<<<dim3(32, 8, 8), 256, 0, stream>>>(XS, conv_W, XC2, XCT2);
    G3R(0, 2, 32, 1, 4096, 144, 2048, XC2, 4096, 2048, LL0, LL0,
        xprojW2, 4096, 2048, LL0, LL0, dtBC, 144, 0, LL0, LL0,
        nullptr, nullptr, 0, 1.f, 1);
    dt_k<<<256, 256, 0, stream>>>(dtBC, dt_bias, DT);
    cuma_k<<<dim3(16, 8), 64, 0, stream>>>(DT, A_log, CUMA);
    gemm_f32_k<<<dim3(4, 4, 8), 256, 0, stream>>>(
        512, 512, 64, dtBC + 80, 144, (long long)512 * 144,
        dtBC + 16, 144, (long long)512 * 144, G, 512, (long long)512 * 512);
    ssd_mfma_k<<<dim3(8, 16, 8), 256, 0, stream>>>(G, CUMA, DT, XCT2, Z, Dv, YS2);

    // ---- weight prep (phase B: S3/S4 now dead) ----
    pairify(stream, outp_W, outp_W2, 11, 1024LL * 2048);
    pairify(stream, aWq, aWq2, 10, 1024LL * 1024);
    pairify(stream, aWk, aWk2, 10, 1024LL * 1024);
    pairify(stream, aWv, aWv2, 10, 1024LL * 1024);
    pairify(stream, aWo, aWo2, 10, 1024LL * 1024);
    pairify(stream, bWk, bWk2, 10, 1024LL * 1024);
    pairify(stream, bWv, bWv2, 10, 1024LL * 1024);

    G3D(0, 8, 32, 1, 4096, 1024, 2048, YS2, 4096, 2048, LL0, LL0,
        outp_W2, 4096, 2048, LL0, LL0, Y1, 1024, 0, LL0, LL0,
        outp_b, T, 1024, 1.f, 1);

    // ---- encoder attention (all MFMA) ----
    layernorm_pair_k<<<4096, 256, 0, stream>>>(Y1, LNY2, n1_w, n1_b, 1024, 4096, LL0);
    G3D(1, 8, 32, 1, 4096, 1024, 1024, LNY2, 2048, 1024, LL0, LL0,
        aWq2, 2048, 1024, LL0, LL0, QA2, 2048, 1024, LL0, LL0,
        nullptr, nullptr, 0, 1.f, 1);
    G3D(1, 8, 32, 1, 4096, 1024, 1024, LNY2, 2048, 1024, LL0, LL0,
        aWk2, 2048, 1024, LL0, LL0, KA2, 2048, 1024, LL0, LL0,
        nullptr, nullptr, 0, 1.f, 1);
    G3D(2, 8, 32, 1, 4096, 1024, 1024, LNY2, 2048, 1024, LL0, LL0,
        aWv2, 2048, 1024, LL0, LL0, VT2, 1024, 512, (long long)1024 * 1024, LL0,
        nullptr, nullptr, 0, 1.f, 1);
    G3D(0, 4, 4, 32, 512, 512, 256,
        QA2, 2048, 1024, (long long)512 * 2048, 256,
        KA2, 2048, 1024, (long long)512 * 2048, 256,
        SA, 512, 0, (long long)4 * 512 * 512, (long long)512 * 512,
        nullptr, nullptr, 0, 1.f / 16.f, 4);
    softmax_pair_k<<<16384, 256, 0, stream>>>(SA, P2);
    G3D(1, 2, 4, 32, 512, 256, 512,
        P2, 1024, 512, (long long)4 * 512 * 1024, (long long)512 * 1024,
        VT2, 1024, 512, (long long)1024 * 1024, (long long)256 * 1024,
        OA2, 2048, 1024, (long long)512 * 2048, 256,
        nullptr, nullptr, 0, 1.f, 4);
    G3D(1, 8, 32, 1, 4096, 1024, 1024, OA2, 2048, 1024, LL0, LL0,
        aWo2, 2048, 1024, LL0, LL0, Y22, 2048, 1024, LL0, LL0,
        aWo_b, Y1, 1024, 1.f, 1);

    // ---- quantize ----
    G3R(0, 1, 32, 1, 4096, 64, 1024, Y22, 2048, 1024, LL0, LL0,
        hW2, 2048, 1024, LL0, LL0, G1, 64, 0, LL0, LL0,
        h_b, nullptr, 0, 1.f, 1);
    hc_quant_k<<<4096, 64, 0, stream>>>(G1, h_lnw, h_lnb, HCQ2);

    // ---- decoder (collapsed masked rows) ----
    G3D(0, 8, 32, 1, 4096, 1024, 64, HCQ2, 128, 64, LL0, LL0,
        e2dW2, 128, 64, LL0, LL0, DXV, 1024, 0, LL0, LL0,
        nullptr, nullptr, 0, 1.f, 1);
    dxm_k<<<4, 256, 0, stream>>>(mtok, e2d_W, dxm);
    layernorm_k<<<1, 256, 0, stream>>>(dxm, lnm, dn_w, dn_b, 1024, 1, LL0);
    layernorm_pair_k<<<4096, 256, 0, stream>>>(DXV, LNDXV2, dn_w, dn_b, 1024, 4096, LL0);
    projm_k<<<12, 256, 0, stream>>>(lnm, bWq, bWk, bWv, qm, km, vm);
    G1D(0, 8, 32, 1, 4096, 1024, 1024, LNDXV2, 2048, 1024, LL0, LL0,
        bWk2, 2048, 1024, LL0, LL0, Kv, 1024, 0, LL0, LL0,
        nullptr, nullptr, 0, 1.f, 1);
    G1D(0, 8, 32, 1, 4096, 1024, 1024, LNDXV2, 2048, 1024, LL0, LL0,
        bWv2, 2048, 1024, LL0, LL0, Vv, 1024, 0, LL0, LL0,
        nullptr, nullptr, 0, 1.f, 1);
    dec_attn_k<<<dim3(4, 8), 256, 0, stream>>>(Kv, Vv, qm, km, vm, OBm);
    ydm_k<<<32, 256, 0, stream>>>(OBm, bWo, bWo_b, dxm, ydm);
    outm_k<<<64, 256, 0, stream>>>(ydm, dout_W, dout_b, outm);
    bcast_k<<<8192, 256, 0, stream>>>(outm, out);
    #undef G3D
    #undef G3R
    #undef G1D
}